// Round 7
// baseline (357.574 us; speedup 1.0000x reference)
//
#include <hip/hip_runtime.h>
#include <math.h>

#define BATCH 2
#define SEQ   2048
#define HID   1024
#define NHEAD 16
#define DHEAD 64
#define MROWS (BATCH*SEQ)      // 4096
#define SCALE_LOG2E 0.1803368801111244f   // 0.125 * log2(e)

typedef __attribute__((ext_vector_type(8))) short short8;
typedef __attribute__((ext_vector_type(4))) short short4v;
typedef __attribute__((ext_vector_type(4))) float floatx4;
#define MFMA16(a,b,c) __builtin_amdgcn_mfma_f32_16x16x32_bf16(a,b,c,0,0,0)

extern "C" __device__ float __ocml_native_exp2_f32(float);
#define EXP2F(x) __ocml_native_exp2_f32(x)

__device__ __forceinline__ unsigned short f2bf(float x) {   // round-half-up
    union { float f; unsigned u; } v; v.f = x;
    return (unsigned short)((v.u + 0x8000u) >> 16);
}
__device__ __forceinline__ float bf2f(unsigned short s) {
    union { unsigned u; float f; } v; v.u = ((unsigned)s) << 16;
    return v.f;
}
__device__ __forceinline__ unsigned pack_bf16(float lo, float hi) {
    union { float f; unsigned u; } a, b; a.f = lo; b.f = hi;
    return __builtin_amdgcn_perm(b.u + 0x8000u, a.u + 0x8000u, 0x07060302u);
}

// ---------------------------------------------------------------------------
// fp32 -> bf16 bulk convert; blockIdx.y selects among 3 tensors
// ---------------------------------------------------------------------------
__global__ __launch_bounds__(256) void cvt_bf16_kernel(
    const float* __restrict__ i0, const float* __restrict__ i1,
    const float* __restrict__ i2,
    unsigned short* __restrict__ o0, unsigned short* __restrict__ o1,
    unsigned short* __restrict__ o2)
{
    const float* in; unsigned short* out;
    switch (blockIdx.y) {
        case 0:  in = i0; out = o0; break;
        case 1:  in = i1; out = o1; break;
        default: in = i2; out = o2; break;
    }
    const size_t i = ((size_t)blockIdx.x * 256 + threadIdx.x) * 8;
    const float4 a = *(const float4*)&in[i];
    const float4 b = *(const float4*)&in[i + 4];
    uint4 u;
    u.x = pack_bf16(a.x, a.y); u.y = pack_bf16(a.z, a.w);
    u.z = pack_bf16(b.x, b.y); u.w = pack_bf16(b.z, b.w);
    *(uint4*)&out[i] = u;
}

// ---------------------------------------------------------------------------
// 4x W[K][N] fp32 -> Wt[N][K] bf16 in one launch (blockIdx.z selects W)
// ---------------------------------------------------------------------------
__global__ __launch_bounds__(256) void wtrans_kernel(
    const float* __restrict__ W0, const float* __restrict__ W1,
    const float* __restrict__ W2, const float* __restrict__ W3,
    unsigned short* __restrict__ T0, unsigned short* __restrict__ T1,
    unsigned short* __restrict__ T2, unsigned short* __restrict__ T3)
{
    const float* W; unsigned short* Wt;
    switch (blockIdx.z) {
        case 0: W = W0; Wt = T0; break;
        case 1: W = W1; Wt = T1; break;
        case 2: W = W2; Wt = T2; break;
        default: W = W3; Wt = T3; break;
    }
    __shared__ float T[64][68];
    const int tid = threadIdx.x;
    const int k0 = blockIdx.x * 64, n0 = blockIdx.y * 64;
#pragma unroll
    for (int it = 0; it < 4; it++) {
        const int id = it * 256 + tid;
        const int r = id >> 4, c4 = (id & 15) << 2;
        *(float4*)&T[r][c4] = *(const float4*)&W[(size_t)(k0 + r) * HID + n0 + c4];
    }
    __syncthreads();
#pragma unroll
    for (int it = 0; it < 2; it++) {
        const int id = it * 256 + tid;
        const int n = id >> 3, k8 = (id & 7) << 3;
        uint4 u;
        u.x = pack_bf16(T[k8 + 0][n], T[k8 + 1][n]);
        u.y = pack_bf16(T[k8 + 2][n], T[k8 + 3][n]);
        u.z = pack_bf16(T[k8 + 4][n], T[k8 + 5][n]);
        u.w = pack_bf16(T[k8 + 6][n], T[k8 + 7][n]);
        *(uint4*)&Wt[(size_t)(n0 + n) * HID + k0 + k8] = u;
    }
}

// ---------------------------------------------------------------------------
// vb[B*SEQ][HID] bf16 -> vt[B][NH][DH][SEQ] bf16 (per-head transpose)
// ---------------------------------------------------------------------------
__global__ __launch_bounds__(256) void vtrans_kernel(
    const unsigned short* __restrict__ vb, unsigned short* __restrict__ vt)
{
    __shared__ unsigned short T[64][72];
    const int b = blockIdx.z, h = blockIdx.y, l0 = blockIdx.x * 64;
    const int tid = threadIdx.x;
#pragma unroll
    for (int it = 0; it < 2; it++) {
        const int id = it * 256 + tid;
        const int l = id >> 3, c8 = (id & 7) << 3;
        *(uint4*)&T[l][c8] =
            *(const uint4*)&vb[(size_t)(b * SEQ + l0 + l) * HID + h * DHEAD + c8];
    }
    __syncthreads();
#pragma unroll
    for (int it = 0; it < 2; it++) {
        const int id = it * 256 + tid;
        const int d = id >> 3, l8 = (id & 7) << 3;
        ushort4 u0, u1;
        u0.x = T[l8 + 0][d]; u0.y = T[l8 + 1][d];
        u0.z = T[l8 + 2][d]; u0.w = T[l8 + 3][d];
        u1.x = T[l8 + 4][d]; u1.y = T[l8 + 5][d];
        u1.z = T[l8 + 6][d]; u1.w = T[l8 + 7][d];
        const size_t o = ((size_t)(b * NHEAD + h) * DHEAD + d) * SEQ + l0 + l8;
        *(ushort4*)&vt[o] = u0;
        *(ushort4*)&vt[o + 4] = u1;
    }
}

// ---------------------------------------------------------------------------
// MFMA GEMM, 128x128 tile, BK=64, bf16 A/B, fp32 accumulate (R5-proven form).
// Optional per-row gate on A (final GEMM). B pre-transposed bf16 [N][K].
// ---------------------------------------------------------------------------
__global__ __launch_bounds__(256) void gemm_mfma_kernel(
    const unsigned short* __restrict__ Ab, const unsigned short* __restrict__ Bt,
    const float* __restrict__ bias,
    const float* __restrict__ gate_cs, const float* __restrict__ gate_th,
    float* __restrict__ Cf, unsigned short* __restrict__ Cb,
    int M, int N, int K)
{
    __shared__ unsigned short As[128][72];
    __shared__ unsigned short Bs[128][72];
    const int tid = threadIdx.x;
    const int w = tid >> 6, lane = tid & 63;
    const int c = lane & 15, quad = lane >> 4;
    const int m0 = blockIdx.x * 128, n0 = blockIdx.y * 128;
    const int wm = (w >> 1) * 64, wn = (w & 1) * 64;

    bool grow[4] = {true, true, true, true};
    if (gate_cs) {
#pragma unroll
        for (int it = 0; it < 4; it++) {
            const int r = (it * 256 + tid) >> 3;
            grow[it] = (gate_cs[m0 + r] - gate_th[m0 + r]) > 0.f;
        }
    }

    floatx4 acc[4][4];
#pragma unroll
    for (int i = 0; i < 4; i++)
#pragma unroll
        for (int j = 0; j < 4; j++) acc[i][j] = (floatx4){0.f, 0.f, 0.f, 0.f};

    for (int kc = 0; kc < K; kc += 64) {
        __syncthreads();
#pragma unroll
        for (int it = 0; it < 4; it++) {
            const int id = it * 256 + tid;
            const int r = id >> 3, c8 = (id & 7) << 3;
            uint4 u = *(const uint4*)&Ab[(size_t)(m0 + r) * K + kc + c8];
            if (!grow[it]) { u.x = 0; u.y = 0; u.z = 0; u.w = 0; }
            *(uint4*)&As[r][c8] = u;
            *(uint4*)&Bs[r][c8] = *(const uint4*)&Bt[(size_t)(n0 + r) * K + kc + c8];
        }
        __syncthreads();
#pragma unroll
        for (int kk = 0; kk < 2; kk++) {
            short8 af[4], bf[4];
#pragma unroll
            for (int mt = 0; mt < 4; mt++)
                af[mt] = *(const short8*)&As[wm + mt * 16 + c][kk * 32 + quad * 8];
#pragma unroll
            for (int nt = 0; nt < 4; nt++)
                bf[nt] = *(const short8*)&Bs[wn + nt * 16 + c][kk * 32 + quad * 8];
#pragma unroll
            for (int mt = 0; mt < 4; mt++)
#pragma unroll
                for (int nt = 0; nt < 4; nt++)
                    acc[mt][nt] = MFMA16(af[mt], bf[nt], acc[mt][nt]);
        }
    }

#pragma unroll
    for (int nt = 0; nt < 4; nt++) {
        const int n = n0 + wn + nt * 16 + c;
        const float bb = bias[n];
#pragma unroll
        for (int mt = 0; mt < 4; mt++) {
            const int m = m0 + wm + mt * 16 + quad * 4;
#pragma unroll
            for (int r = 0; r < 4; r++) {
                const float val = acc[mt][nt][r] + bb;
                const size_t off = (size_t)(m + r) * N + n;
                if (Cf) Cf[off] = val;
                if (Cb) Cb[off] = f2bf(val);
            }
        }
    }
}

// ---------------------------------------------------------------------------
// threshold[row] = sum_h qb*kb*Wt + bt  (bf16 inputs, fp32 accumulate)
// ---------------------------------------------------------------------------
__global__ __launch_bounds__(256) void threshold_kernel(
    const unsigned short* __restrict__ qb, const unsigned short* __restrict__ kb,
    const float* __restrict__ Wt, const float* __restrict__ bt,
    float* __restrict__ thr)
{
    const int w = threadIdx.x >> 6, lane = threadIdx.x & 63;
    const int row = blockIdx.x * 4 + w;
    const unsigned short* qr = qb + (size_t)row * HID;
    const unsigned short* kr = kb + (size_t)row * HID;
    float s = 0.f;
#pragma unroll
    for (int ii = 0; ii < 2; ii++) {
        const int base = ii * 512 + lane * 8;
        const ushort4 q0 = *(const ushort4*)&qr[base];
        const ushort4 q1 = *(const ushort4*)&qr[base + 4];
        const ushort4 k0 = *(const ushort4*)&kr[base];
        const ushort4 k1 = *(const ushort4*)&kr[base + 4];
        const float4 w0 = *(const float4*)&Wt[base];
        const float4 w1 = *(const float4*)&Wt[base + 4];
        s += bf2f(q0.x) * bf2f(k0.x) * w0.x + bf2f(q0.y) * bf2f(k0.y) * w0.y +
             bf2f(q0.z) * bf2f(k0.z) * w0.z + bf2f(q0.w) * bf2f(k0.w) * w0.w +
             bf2f(q1.x) * bf2f(k1.x) * w1.x + bf2f(q1.y) * bf2f(k1.y) * w1.y +
             bf2f(q1.z) * bf2f(k1.z) * w1.z + bf2f(q1.w) * bf2f(k1.w) * w1.w;
    }
#pragma unroll
    for (int off = 32; off > 0; off >>= 1) s += __shfl_xor(s, off, 64);
    if (lane == 0) thr[row] = s + bt[0];
}

// ---------------------------------------------------------------------------
// Pass 1 (MFMA): 128 q-rows/block, 4 FAT waves (32 q each, 2 row-tiles).
// K/V fragment reads amortized over 2 row-tiles -> ~30% less LDS-pipe work.
// Qs staging overlays Ks/Vs (dead after frag hoist). XCD-swizzled grid.
// ---------------------------------------------------------------------------
__global__ __launch_bounds__(256) void flash_mfma_kernel(
    const unsigned short* __restrict__ qb, const unsigned short* __restrict__ kb,
    const unsigned short* __restrict__ vt, const unsigned char* __restrict__ mask,
    unsigned short* __restrict__ att, float* __restrict__ zinv_out)
{
    const int n = blockIdx.x;
    const int xcd = n & 7, t = n >> 3;
    const int g = xcd + 8 * (t >> 4);
    const int qblk = t & 15;
    const int h = g & 15, b = g >> 4;
    const int q0 = qblk * 128;

    const int tid = threadIdx.x;
    const int w = tid >> 6, lane = tid & 63;
    const int c = lane & 15, quad = lane >> 4;

    __shared__ unsigned short SM[18048];          // 36096 B
    unsigned short* Ks = SM;                      // [64][72]
    unsigned short* Vs = SM + 4608;               // [64][72]  Vs[d][j]
    unsigned short* Ps = SM + 9216;               // [8][16][68]
    float* mbf = (float*)(SM + 17920);            // [64]
    unsigned short* Qs = SM;                      // staging alias [128][72]

    const size_t hoff = (size_t)h * DHEAD;
#pragma unroll
    for (int it = 0; it < 4; it++) {
        const int id = it * 256 + tid;
        const int r = id >> 3, c8 = (id & 7) << 3;
        *(uint4*)&Qs[r * 72 + c8] =
            *(const uint4*)&qb[(size_t)(b * SEQ + q0 + r) * HID + hoff + c8];
    }
    __syncthreads();
    short8 aq[2][2];
#pragma unroll
    for (int s = 0; s < 2; s++) {
        aq[s][0] = *(const short8*)&Qs[(w * 32 + s * 16 + c) * 72 + quad * 8];
        aq[s][1] = *(const short8*)&Qs[(w * 32 + s * 16 + c) * 72 + 32 + quad * 8];
    }

    floatx4 acc[2][4];
#pragma unroll
    for (int s = 0; s < 2; s++)
#pragma unroll
        for (int dt = 0; dt < 4; dt++) acc[s][dt] = (floatx4){0.f, 0.f, 0.f, 0.f};
    float zp[2][4] = {{0.f, 0.f, 0.f, 0.f}, {0.f, 0.f, 0.f, 0.f}};
    const size_t vtbase = (size_t)(b * NHEAD + h) * DHEAD * SEQ;

    for (int kc = 0; kc < SEQ; kc += 64) {
        __syncthreads();   // Qs reads (pre-loop) / Ps+Vs reads (prev iter) done
#pragma unroll
        for (int it = 0; it < 2; it++) {
            const int id = it * 256 + tid;
            const int r = id >> 3, c8 = (id & 7) << 3;
            *(uint4*)&Ks[r * 72 + c8] =
                *(const uint4*)&kb[(size_t)(b * SEQ + kc + r) * HID + hoff + c8];
            *(uint4*)&Vs[r * 72 + c8] =
                *(const uint4*)&vt[vtbase + (size_t)r * SEQ + kc + c8];
        }
        if (tid < 64) mbf[tid] = mask[(size_t)b * SEQ + kc + tid] ? -1e9f : 0.f;
        __syncthreads();

#pragma unroll
        for (int nt = 0; nt < 4; nt++) {
            const short8 bk0 = *(const short8*)&Ks[(nt * 16 + c) * 72 + quad * 8];
            const short8 bk1 = *(const short8*)&Ks[(nt * 16 + c) * 72 + 32 + quad * 8];
            const float mb = mbf[nt * 16 + c];
#pragma unroll
            for (int s = 0; s < 2; s++) {
                floatx4 sv = (floatx4){0.f, 0.f, 0.f, 0.f};
                sv = MFMA16(aq[s][0], bk0, sv);
                sv = MFMA16(aq[s][1], bk1, sv);
#pragma unroll
                for (int r = 0; r < 4; r++) {
                    const float p = EXP2F(fmaf(sv[r], SCALE_LOG2E, mb));
                    zp[s][r] += p;
                    Ps[((2 * w + s) * 16 + quad * 4 + r) * 68 + nt * 16 + c] = f2bf(p);
                }
            }
        }

        short8 ap[2][2];
#pragma unroll
        for (int s = 0; s < 2; s++) {
            const unsigned short* pr = &Ps[((2 * w + s) * 16 + c) * 68];
            short4v p00 = *(const short4v*)&pr[quad * 8];
            short4v p01 = *(const short4v*)&pr[quad * 8 + 4];
            short4v p10 = *(const short4v*)&pr[32 + quad * 8];
            short4v p11 = *(const short4v*)&pr[32 + quad * 8 + 4];
            ap[s][0] = __builtin_shufflevector(p00, p01, 0, 1, 2, 3, 4, 5, 6, 7);
            ap[s][1] = __builtin_shufflevector(p10, p11, 0, 1, 2, 3, 4, 5, 6, 7);
        }
#pragma unroll
        for (int dt = 0; dt < 4; dt++) {
            const short8 bv0 = *(const short8*)&Vs[(dt * 16 + c) * 72 + quad * 8];
            const short8 bv1 = *(const short8*)&Vs[(dt * 16 + c) * 72 + 32 + quad * 8];
#pragma unroll
            for (int s = 0; s < 2; s++) {
                acc[s][dt] = MFMA16(ap[s][0], bv0, acc[s][dt]);
                acc[s][dt] = MFMA16(ap[s][1], bv1, acc[s][dt]);
            }
        }
    }

#pragma unroll
    for (int s = 0; s < 2; s++) {
#pragma unroll
        for (int r = 0; r < 4; r++) {
            float z = zp[s][r];
            z += __shfl_xor(z, 1, 64); z += __shfl_xor(z, 2, 64);
            z += __shfl_xor(z, 4, 64); z += __shfl_xor(z, 8, 64);
            zp[s][r] = 1.0f / (z + 1e-30f);
        }
#pragma unroll
        for (int dt = 0; dt < 4; dt++)
#pragma unroll
            for (int r = 0; r < 4; r++)
                att[(size_t)(b * SEQ + q0 + w * 32 + s * 16 + quad * 4 + r) * HID +
                    hoff + dt * 16 + c] = f2bf(acc[s][dt][r] * zp[s][r]);
        if (c == 0) {
            const size_t zb = (size_t)(b * NHEAD + h) * SEQ + q0 + w * 32 + s * 16 +
                              quad * 4;
#pragma unroll
            for (int r = 0; r < 4; r++) zinv_out[zb + r] = zp[s][r];
        }
    }
}

// ---------------------------------------------------------------------------
// Pass 2 (MFMA): 128 k-cols/block, 4 FAT waves (32 k each). Q frag reads
// amortized over 2 k-tiles. Ks staging overlays steady Qs/zs. XCD-swizzled.
// ---------------------------------------------------------------------------
__global__ __launch_bounds__(256) void colsum_mfma_kernel(
    const unsigned short* __restrict__ qb, const unsigned short* __restrict__ kb,
    const unsigned char* __restrict__ mask, const float* __restrict__ zinv,
    float* __restrict__ colsum)
{
    const int n = blockIdx.x;
    const int xcd = n & 7, t = n >> 3;
    const int g = xcd + 8 * (t >> 4);
    const int h = g & 15, b = g >> 4;
    const int k0 = (t & 15) * 128;

    const int tid = threadIdx.x;
    const int w = tid >> 6, lane = tid & 63;
    const int c = lane & 15, quad = lane >> 4;

    __shared__ unsigned short SM[9216];           // 18432 B
    unsigned short* Qs = SM;                      // steady [64][72]
    float* zs = (float*)(SM + 4608);              // [64]
    unsigned short* Kst = SM;                     // staging alias [128][72]

    const size_t hoff = (size_t)h * DHEAD;
#pragma unroll
    for (int it = 0; it < 4; it++) {
        const int id = it * 256 + tid;
        const int r = id >> 3, c8 = (id & 7) << 3;
        *(uint4*)&Kst[r * 72 + c8] =
            *(const uint4*)&kb[(size_t)(b * SEQ + k0 + r) * HID + hoff + c8];
    }
    __syncthreads();
    short8 ak[2][2];
    float mb[2][4];
#pragma unroll
    for (int s = 0; s < 2; s++) {
        ak[s][0] = *(const short8*)&Kst[(w * 32 + s * 16 + c) * 72 + quad * 8];
        ak[s][1] = *(const short8*)&Kst[(w * 32 + s * 16 + c) * 72 + 32 + quad * 8];
#pragma unroll
        for (int r = 0; r < 4; r++)
            mb[s][r] = mask[(size_t)b * SEQ + k0 + w * 32 + s * 16 + quad * 4 + r]
                       ? -1e9f : 0.f;
    }

    float cs[2][4] = {{0.f, 0.f, 0.f, 0.f}, {0.f, 0.f, 0.f, 0.f}};
    const size_t zbase = (size_t)(b * NHEAD + h) * SEQ;

    for (int qc = 0; qc < SEQ; qc += 64) {
        __syncthreads();   // Kst frag reads / prev-iter Qs reads done
#pragma unroll
        for (int it = 0; it < 2; it++) {
            const int id = it * 256 + tid;
            const int r = id >> 3, c8 = (id & 7) << 3;
            *(uint4*)&Qs[r * 72 + c8] =
                *(const uint4*)&qb[(size_t)(b * SEQ + qc + r) * HID + hoff + c8];
        }
        if (tid < 64) zs[tid] = zinv[zbase + qc + tid];
        __syncthreads();

#pragma unroll
        for (int qt = 0; qt < 4; qt++) {
            const short8 bq0 = *(const short8*)&Qs[(qt * 16 + c) * 72 + quad * 8];
            const short8 bq1 = *(const short8*)&Qs[(qt * 16 + c) * 72 + 32 + quad * 8];
            const float zi = zs[qt * 16 + c];
#pragma unroll
            for (int s = 0; s < 2; s++) {
                floatx4 sv = (floatx4){0.f, 0.f, 0.f, 0.f};
                sv = MFMA16(ak[s][0], bq0, sv);
                sv = MFMA16(ak[s][1], bq1, sv);
#pragma unroll
                for (int r = 0; r < 4; r++)
                    cs[s][r] += EXP2F(fmaf(sv[r], SCALE_LOG2E, mb[s][r])) * zi;
            }
        }
    }

#pragma unroll
    for (int s = 0; s < 2; s++)
#pragma unroll
        for (int r = 0; r < 4; r++) {
            float v = cs[s][r];
            v += __shfl_xor(v, 1, 64); v += __shfl_xor(v, 2, 64);
            v += __shfl_xor(v, 4, 64); v += __shfl_xor(v, 8, 64);
            if (c == 0)
                atomicAdd(&colsum[(size_t)b * SEQ + k0 + w * 32 + s * 16 +
                                  quad * 4 + r], v);
        }
}

// ---------------------------------------------------------------------------
extern "C" void kernel_launch(void* const* d_in, const int* in_sizes, int n_in,
                              void* d_out, int out_size, void* d_ws, size_t ws_size,
                              hipStream_t stream)
{
    const float* v  = (const float*)d_in[0];
    const float* k  = (const float*)d_in[1];
    const float* q  = (const float*)d_in[2];
    const unsigned char* mask = (const unsigned char*)d_in[3];
    const float* Wv = (const float*)d_in[4];
    const float* bv = (const float*)d_in[5];
    const float* Wk = (const float*)d_in[6];
    const float* bk = (const float*)d_in[7];
    const float* Wq = (const float*)d_in[8];
    const float* bq = (const float*)d_in[9];
    const float* Wt = (const float*)d_in[10];
    const float* bt = (const float*)d_in[11];
    const float* Wm = (const float*)d_in[12];
    const float* bm = (const float*)d_in[13];
    float* out = (float*)d_out;

    const size_t NE = (size_t)MROWS * HID;
    const size_t WE = (size_t)HID * HID;
    unsigned short* qa   = (unsigned short*)d_ws;
    unsigned short* ka   = qa  + NE;
    unsigned short* va   = ka  + NE;
    unsigned short* qp   = va  + NE;
    unsigned short* kp   = qp  + NE;
    unsigned short* vp   = kp  + NE;
    unsigned short* WqT  = vp  + NE;
    unsigned short* WkT  = WqT + WE;
    unsigned short* WvT  = WkT + WE;
    unsigned short* WmT  = WvT + WE;
    float* thr    = (float*)(WmT + WE);
    float* zinv   = thr  + MROWS;
    float* colsum = zinv + (size_t)BATCH * NHEAD * SEQ;
    // buffer reuse (stream-ordered, live ranges don't overlap):
    unsigned short* attb = qa;   // qa dead after q-projection GEMM
    unsigned short* vtb  = ka;   // ka dead after k-projection GEMM

    wtrans_kernel<<<dim3(HID / 64, HID / 64, 4), 256, 0, stream>>>(
        Wq, Wk, Wv, Wm, WqT, WkT, WvT, WmT);

    cvt_bf16_kernel<<<dim3((unsigned)(NE / (256 * 8)), 3), 256, 0, stream>>>(
        q, k, v, qa, ka, va);

    const dim3 gg(MROWS / 128, HID / 128);
    gemm_mfma_kernel<<<gg, 256, 0, stream>>>(qa, WqT, bq, nullptr, nullptr,
                                             nullptr, qp, MROWS, HID, HID);
    gemm_mfma_kernel<<<gg, 256, 0, stream>>>(ka, WkT, bk, nullptr, nullptr,
                                             nullptr, kp, MROWS, HID, HID);
    gemm_mfma_kernel<<<gg, 256, 0, stream>>>(va, WvT, bv, nullptr, nullptr,
                                             nullptr, vp, MROWS, HID, HID);

    vtrans_kernel<<<dim3(SEQ / 64, NHEAD, BATCH), 256, 0, stream>>>(vp, vtb);

    threshold_kernel<<<MROWS / 4, 256, 0, stream>>>(qp, kp, Wt, bt, thr);

    flash_mfma_kernel<<<BATCH * NHEAD * (SEQ / 128), 256, 0, stream>>>(
        qp, kp, vtb, mask, attb, zinv);

    hipMemsetAsync(colsum, 0, MROWS * sizeof(float), stream);
    colsum_mfma_kernel<<<BATCH * NHEAD * (SEQ / 128), 256, 0, stream>>>(
        qp, kp, mask, zinv, colsum);

    gemm_mfma_kernel<<<gg, 256, 0, stream>>>(attb, WmT, bm, colsum, thr,
                                             out, nullptr, MROWS, HID, HID);
}

// Round 8
// 287.823 us; speedup vs baseline: 1.2423x; 1.2423x over previous
//
#include <hip/hip_runtime.h>
#include <math.h>

#define BATCH 2
#define SEQ   2048
#define HID   1024
#define NHEAD 16
#define DHEAD 64
#define MROWS (BATCH*SEQ)      // 4096
#define SCALE_LOG2E 0.1803368801111244f   // 0.125 * log2(e)

typedef __attribute__((ext_vector_type(8))) short short8;
typedef __attribute__((ext_vector_type(4))) short short4v;
typedef __attribute__((ext_vector_type(4))) float floatx4;
#define MFMA16(a,b,c) __builtin_amdgcn_mfma_f32_16x16x32_bf16(a,b,c,0,0,0)

extern "C" __device__ float __ocml_native_exp2_f32(float);
#define EXP2F(x) __ocml_native_exp2_f32(x)

__device__ __forceinline__ unsigned short f2bf(float x) {   // round-half-up
    union { float f; unsigned u; } v; v.f = x;
    return (unsigned short)((v.u + 0x8000u) >> 16);
}
__device__ __forceinline__ float bf2f(unsigned short s) {
    union { unsigned u; float f; } v; v.u = ((unsigned)s) << 16;
    return v.f;
}
__device__ __forceinline__ unsigned pack_bf16(float lo, float hi) {
    union { float f; unsigned u; } a, b; a.f = lo; b.f = hi;
    return __builtin_amdgcn_perm(b.u + 0x8000u, a.u + 0x8000u, 0x07060302u);
}

// ---------------------------------------------------------------------------
// fp32 -> bf16 bulk convert; blockIdx.y selects among 3 tensors
// ---------------------------------------------------------------------------
__global__ __launch_bounds__(256) void cvt_bf16_kernel(
    const float* __restrict__ i0, const float* __restrict__ i1,
    const float* __restrict__ i2,
    unsigned short* __restrict__ o0, unsigned short* __restrict__ o1,
    unsigned short* __restrict__ o2)
{
    const float* in; unsigned short* out;
    switch (blockIdx.y) {
        case 0:  in = i0; out = o0; break;
        case 1:  in = i1; out = o1; break;
        default: in = i2; out = o2; break;
    }
    const size_t i = ((size_t)blockIdx.x * 256 + threadIdx.x) * 8;
    const float4 a = *(const float4*)&in[i];
    const float4 b = *(const float4*)&in[i + 4];
    uint4 u;
    u.x = pack_bf16(a.x, a.y); u.y = pack_bf16(a.z, a.w);
    u.z = pack_bf16(b.x, b.y); u.w = pack_bf16(b.z, b.w);
    *(uint4*)&out[i] = u;
}

// ---------------------------------------------------------------------------
// 4x W[K][N] fp32 -> Wt[N][K] bf16 in one launch (blockIdx.z selects W)
// ---------------------------------------------------------------------------
__global__ __launch_bounds__(256) void wtrans_kernel(
    const float* __restrict__ W0, const float* __restrict__ W1,
    const float* __restrict__ W2, const float* __restrict__ W3,
    unsigned short* __restrict__ T0, unsigned short* __restrict__ T1,
    unsigned short* __restrict__ T2, unsigned short* __restrict__ T3)
{
    const float* W; unsigned short* Wt;
    switch (blockIdx.z) {
        case 0: W = W0; Wt = T0; break;
        case 1: W = W1; Wt = T1; break;
        case 2: W = W2; Wt = T2; break;
        default: W = W3; Wt = T3; break;
    }
    __shared__ float T[64][68];
    const int tid = threadIdx.x;
    const int k0 = blockIdx.x * 64, n0 = blockIdx.y * 64;
#pragma unroll
    for (int it = 0; it < 4; it++) {
        const int id = it * 256 + tid;
        const int r = id >> 4, c4 = (id & 15) << 2;
        *(float4*)&T[r][c4] = *(const float4*)&W[(size_t)(k0 + r) * HID + n0 + c4];
    }
    __syncthreads();
#pragma unroll
    for (int it = 0; it < 2; it++) {
        const int id = it * 256 + tid;
        const int n = id >> 3, k8 = (id & 7) << 3;
        uint4 u;
        u.x = pack_bf16(T[k8 + 0][n], T[k8 + 1][n]);
        u.y = pack_bf16(T[k8 + 2][n], T[k8 + 3][n]);
        u.z = pack_bf16(T[k8 + 4][n], T[k8 + 5][n]);
        u.w = pack_bf16(T[k8 + 6][n], T[k8 + 7][n]);
        *(uint4*)&Wt[(size_t)(n0 + n) * HID + k0 + k8] = u;
    }
}

// ---------------------------------------------------------------------------
// Fused Q/K/V projection GEMM: grid.z selects {q,k,v}. 128x128 tile, BK=64.
// z<2 writes row-major bf16; z==2 writes vt[b][h][d][seq] directly (ushort4
// along l), deleting the separate V-transpose pass.
// ---------------------------------------------------------------------------
__global__ __launch_bounds__(256) void proj3_mfma_kernel(
    const unsigned short* __restrict__ A0, const unsigned short* __restrict__ A1,
    const unsigned short* __restrict__ A2,
    const unsigned short* __restrict__ B0, const unsigned short* __restrict__ B1,
    const unsigned short* __restrict__ B2,
    const float* __restrict__ bi0, const float* __restrict__ bi1,
    const float* __restrict__ bi2,
    unsigned short* __restrict__ C0, unsigned short* __restrict__ C1,
    unsigned short* __restrict__ vt)
{
    const unsigned short *Ab, *Bt; const float* bias;
    switch (blockIdx.z) {
        case 0:  Ab = A0; Bt = B0; bias = bi0; break;
        case 1:  Ab = A1; Bt = B1; bias = bi1; break;
        default: Ab = A2; Bt = B2; bias = bi2; break;
    }
    __shared__ unsigned short As[128][72];
    __shared__ unsigned short Bs[128][72];
    const int tid = threadIdx.x;
    const int w = tid >> 6, lane = tid & 63;
    const int c = lane & 15, quad = lane >> 4;
    const int m0 = blockIdx.x * 128, n0 = blockIdx.y * 128;
    const int wm = (w >> 1) * 64, wn = (w & 1) * 64;

    floatx4 acc[4][4];
#pragma unroll
    for (int i = 0; i < 4; i++)
#pragma unroll
        for (int j = 0; j < 4; j++) acc[i][j] = (floatx4){0.f, 0.f, 0.f, 0.f};

    for (int kc = 0; kc < HID; kc += 64) {
        __syncthreads();
#pragma unroll
        for (int it = 0; it < 4; it++) {
            const int id = it * 256 + tid;
            const int r = id >> 3, c8 = (id & 7) << 3;
            *(uint4*)&As[r][c8] = *(const uint4*)&Ab[(size_t)(m0 + r) * HID + kc + c8];
            *(uint4*)&Bs[r][c8] = *(const uint4*)&Bt[(size_t)(n0 + r) * HID + kc + c8];
        }
        __syncthreads();
#pragma unroll
        for (int kk = 0; kk < 2; kk++) {
            short8 af[4], bf[4];
#pragma unroll
            for (int mt = 0; mt < 4; mt++)
                af[mt] = *(const short8*)&As[wm + mt * 16 + c][kk * 32 + quad * 8];
#pragma unroll
            for (int nt = 0; nt < 4; nt++)
                bf[nt] = *(const short8*)&Bs[wn + nt * 16 + c][kk * 32 + quad * 8];
#pragma unroll
            for (int mt = 0; mt < 4; mt++)
#pragma unroll
                for (int nt = 0; nt < 4; nt++)
                    acc[mt][nt] = MFMA16(af[mt], bf[nt], acc[mt][nt]);
        }
    }

    if (blockIdx.z < 2) {
        unsigned short* Cb = blockIdx.z == 0 ? C0 : C1;
#pragma unroll
        for (int nt = 0; nt < 4; nt++) {
            const int n = n0 + wn + nt * 16 + c;
            const float bb = bias[n];
#pragma unroll
            for (int mt = 0; mt < 4; mt++) {
                const int m = m0 + wm + mt * 16 + quad * 4;
#pragma unroll
                for (int r = 0; r < 4; r++)
                    Cb[(size_t)(m + r) * HID + n] = f2bf(acc[mt][nt][r] + bb);
            }
        }
    } else {
        // vt[((b*NH+h)*DH+d)*SEQ + l]; m = b*SEQ+l, n = h*DH+d
#pragma unroll
        for (int nt = 0; nt < 4; nt++) {
            const int n = n0 + wn + nt * 16 + c;
            const float bb = bias[n];
            const int h = n >> 6, d = n & 63;
#pragma unroll
            for (int mt = 0; mt < 4; mt++) {
                const int m = m0 + wm + mt * 16 + quad * 4;
                const int b = m >> 11, l = m & 2047;
                ushort4 u;
                u.x = f2bf(acc[mt][nt][0] + bb);
                u.y = f2bf(acc[mt][nt][1] + bb);
                u.z = f2bf(acc[mt][nt][2] + bb);
                u.w = f2bf(acc[mt][nt][3] + bb);
                *(ushort4*)&vt[((size_t)(b * NHEAD + h) * DHEAD + d) * SEQ + l] = u;
            }
        }
    }
}

// ---------------------------------------------------------------------------
// Final GEMM with per-row gate on A: out = gate(A) @ Wm^T + bm (fp32 out)
// ---------------------------------------------------------------------------
__global__ __launch_bounds__(256) void gemm_gate_kernel(
    const unsigned short* __restrict__ Ab, const unsigned short* __restrict__ Bt,
    const float* __restrict__ bias,
    const float* __restrict__ gate_cs, const float* __restrict__ gate_th,
    float* __restrict__ Cf)
{
    __shared__ unsigned short As[128][72];
    __shared__ unsigned short Bs[128][72];
    const int tid = threadIdx.x;
    const int w = tid >> 6, lane = tid & 63;
    const int c = lane & 15, quad = lane >> 4;
    const int m0 = blockIdx.x * 128, n0 = blockIdx.y * 128;
    const int wm = (w >> 1) * 64, wn = (w & 1) * 64;

    bool grow[4];
#pragma unroll
    for (int it = 0; it < 4; it++) {
        const int r = (it * 256 + tid) >> 3;
        grow[it] = (gate_cs[m0 + r] - gate_th[m0 + r]) > 0.f;
    }

    floatx4 acc[4][4];
#pragma unroll
    for (int i = 0; i < 4; i++)
#pragma unroll
        for (int j = 0; j < 4; j++) acc[i][j] = (floatx4){0.f, 0.f, 0.f, 0.f};

    for (int kc = 0; kc < HID; kc += 64) {
        __syncthreads();
#pragma unroll
        for (int it = 0; it < 4; it++) {
            const int id = it * 256 + tid;
            const int r = id >> 3, c8 = (id & 7) << 3;
            uint4 u = *(const uint4*)&Ab[(size_t)(m0 + r) * HID + kc + c8];
            if (!grow[it]) { u.x = 0; u.y = 0; u.z = 0; u.w = 0; }
            *(uint4*)&As[r][c8] = u;
            *(uint4*)&Bs[r][c8] = *(const uint4*)&Bt[(size_t)(n0 + r) * HID + kc + c8];
        }
        __syncthreads();
#pragma unroll
        for (int kk = 0; kk < 2; kk++) {
            short8 af[4], bf[4];
#pragma unroll
            for (int mt = 0; mt < 4; mt++)
                af[mt] = *(const short8*)&As[wm + mt * 16 + c][kk * 32 + quad * 8];
#pragma unroll
            for (int nt = 0; nt < 4; nt++)
                bf[nt] = *(const short8*)&Bs[wn + nt * 16 + c][kk * 32 + quad * 8];
#pragma unroll
            for (int mt = 0; mt < 4; mt++)
#pragma unroll
                for (int nt = 0; nt < 4; nt++)
                    acc[mt][nt] = MFMA16(af[mt], bf[nt], acc[mt][nt]);
        }
    }

#pragma unroll
    for (int nt = 0; nt < 4; nt++) {
        const int n = n0 + wn + nt * 16 + c;
        const float bb = bias[n];
#pragma unroll
        for (int mt = 0; mt < 4; mt++) {
            const int m = m0 + wm + mt * 16 + quad * 4;
#pragma unroll
            for (int r = 0; r < 4; r++)
                Cf[(size_t)(m + r) * HID + n] = acc[mt][nt][r] + bb;
        }
    }
}

// ---------------------------------------------------------------------------
// threshold[row] = sum_h qb*kb*Wt + bt; also zeroes colsum[row]
// ---------------------------------------------------------------------------
__global__ __launch_bounds__(256) void threshold_kernel(
    const unsigned short* __restrict__ qb, const unsigned short* __restrict__ kb,
    const float* __restrict__ Wt, const float* __restrict__ bt,
    float* __restrict__ thr, float* __restrict__ colsum)
{
    const int w = threadIdx.x >> 6, lane = threadIdx.x & 63;
    const int row = blockIdx.x * 4 + w;
    const unsigned short* qr = qb + (size_t)row * HID;
    const unsigned short* kr = kb + (size_t)row * HID;
    float s = 0.f;
#pragma unroll
    for (int ii = 0; ii < 2; ii++) {
        const int base = ii * 512 + lane * 8;
        const ushort4 q0 = *(const ushort4*)&qr[base];
        const ushort4 q1 = *(const ushort4*)&qr[base + 4];
        const ushort4 k0 = *(const ushort4*)&kr[base];
        const ushort4 k1 = *(const ushort4*)&kr[base + 4];
        const float4 w0 = *(const float4*)&Wt[base];
        const float4 w1 = *(const float4*)&Wt[base + 4];
        s += bf2f(q0.x) * bf2f(k0.x) * w0.x + bf2f(q0.y) * bf2f(k0.y) * w0.y +
             bf2f(q0.z) * bf2f(k0.z) * w0.z + bf2f(q0.w) * bf2f(k0.w) * w0.w +
             bf2f(q1.x) * bf2f(k1.x) * w1.x + bf2f(q1.y) * bf2f(k1.y) * w1.y +
             bf2f(q1.z) * bf2f(k1.z) * w1.z + bf2f(q1.w) * bf2f(k1.w) * w1.w;
    }
#pragma unroll
    for (int off = 32; off > 0; off >>= 1) s += __shfl_xor(s, off, 64);
    if (lane == 0) { thr[row] = s + bt[0]; colsum[row] = 0.f; }
}

// ---------------------------------------------------------------------------
// Pass 1 (MFMA): 128 q-rows/block, 8 thin waves (16 q each). Reg-dbuf K/V
// staging; Qs staging overlays the steady Ks/Vs/Ps region. XCD-swizzled.
// ---------------------------------------------------------------------------
__global__ __launch_bounds__(512) void flash_mfma_kernel(
    const unsigned short* __restrict__ qb, const unsigned short* __restrict__ kb,
    const unsigned short* __restrict__ vt, const unsigned char* __restrict__ mask,
    unsigned short* __restrict__ att, float* __restrict__ zinv_out)
{
    const int n = blockIdx.x;
    const int xcd = n & 7, t = n >> 3;
    const int g = xcd + 8 * (t >> 4);
    const int qblk = t & 15;
    const int h = g & 15, b = g >> 4;
    const int q0 = qblk * 128;

    const int tid = threadIdx.x;
    const int w = tid >> 6, lane = tid & 63;
    const int c = lane & 15, quad = lane >> 4;

    __shared__ unsigned short SM[18048];          // 36096 B
    unsigned short* Ks = SM;                      // [64][72]
    unsigned short* Vs = SM + 4608;               // [64][72]  Vs[d][j]
    unsigned short* Ps = SM + 9216;               // [8][16][68]
    float* mbf = (float*)(SM + 17920);            // [64]
    unsigned short* Qs = SM;                      // staging alias [128][72]

    const size_t hoff = (size_t)h * DHEAD;
#pragma unroll
    for (int it = 0; it < 2; it++) {
        const int gg = it * 512 + tid;
        const int r = gg >> 3, c8 = (gg & 7) << 3;
        *(uint4*)&Qs[r * 72 + c8] =
            *(const uint4*)&qb[(size_t)(b * SEQ + q0 + r) * HID + hoff + c8];
    }
    __syncthreads();
    const short8 aq0 = *(const short8*)&Qs[(w * 16 + c) * 72 + quad * 8];
    const short8 aq1 = *(const short8*)&Qs[(w * 16 + c) * 72 + 32 + quad * 8];

    floatx4 acc_o[4];
#pragma unroll
    for (int dt = 0; dt < 4; dt++) acc_o[dt] = (floatx4){0.f, 0.f, 0.f, 0.f};
    float zp[4] = {0.f, 0.f, 0.f, 0.f};
    const size_t vtbase = (size_t)(b * NHEAD + h) * DHEAD * SEQ;

    const int sr = tid >> 3, sc8 = (tid & 7) << 3;
    uint4 kreg = *(const uint4*)&kb[(size_t)(b * SEQ + sr) * HID + hoff + sc8];
    uint4 vreg = *(const uint4*)&vt[vtbase + (size_t)sr * SEQ + sc8];
    float mreg = 0.f;
    if (tid < 64) mreg = mask[(size_t)b * SEQ + tid] ? -1e9f : 0.f;

    for (int kc = 0; kc < SEQ; kc += 64) {
        __syncthreads();
        *(uint4*)&Ks[sr * 72 + sc8] = kreg;
        *(uint4*)&Vs[sr * 72 + sc8] = vreg;
        if (tid < 64) mbf[tid] = mreg;
        __syncthreads();
        if (kc + 64 < SEQ) {
            kreg = *(const uint4*)&kb[(size_t)(b * SEQ + kc + 64 + sr) * HID + hoff + sc8];
            vreg = *(const uint4*)&vt[vtbase + (size_t)sr * SEQ + kc + 64 + sc8];
            if (tid < 64) mreg = mask[(size_t)b * SEQ + kc + 64 + tid] ? -1e9f : 0.f;
        }

#pragma unroll
        for (int nt = 0; nt < 4; nt++) {
            const short8 bk0 = *(const short8*)&Ks[(nt * 16 + c) * 72 + quad * 8];
            const short8 bk1 = *(const short8*)&Ks[(nt * 16 + c) * 72 + 32 + quad * 8];
            floatx4 s = (floatx4){0.f, 0.f, 0.f, 0.f};
            s = MFMA16(aq0, bk0, s);
            s = MFMA16(aq1, bk1, s);
            const float mb = mbf[nt * 16 + c];
#pragma unroll
            for (int r = 0; r < 4; r++) {
                const float p = EXP2F(fmaf(s[r], SCALE_LOG2E, mb));
                zp[r] += p;
                Ps[(w * 16 + quad * 4 + r) * 68 + nt * 16 + c] = f2bf(p);
            }
        }

        const unsigned short* pr = &Ps[(w * 16 + c) * 68];
        short4v p00 = *(const short4v*)&pr[quad * 8];
        short4v p01 = *(const short4v*)&pr[quad * 8 + 4];
        short4v p10 = *(const short4v*)&pr[32 + quad * 8];
        short4v p11 = *(const short4v*)&pr[32 + quad * 8 + 4];
        const short8 ap0 = __builtin_shufflevector(p00, p01, 0, 1, 2, 3, 4, 5, 6, 7);
        const short8 ap1 = __builtin_shufflevector(p10, p11, 0, 1, 2, 3, 4, 5, 6, 7);
#pragma unroll
        for (int dt = 0; dt < 4; dt++) {
            const short8 bv0 = *(const short8*)&Vs[(dt * 16 + c) * 72 + quad * 8];
            const short8 bv1 = *(const short8*)&Vs[(dt * 16 + c) * 72 + 32 + quad * 8];
            acc_o[dt] = MFMA16(ap0, bv0, acc_o[dt]);
            acc_o[dt] = MFMA16(ap1, bv1, acc_o[dt]);
        }
    }

#pragma unroll
    for (int r = 0; r < 4; r++) {
        float z = zp[r];
        z += __shfl_xor(z, 1, 64); z += __shfl_xor(z, 2, 64);
        z += __shfl_xor(z, 4, 64); z += __shfl_xor(z, 8, 64);
        zp[r] = 1.0f / (z + 1e-30f);
    }

#pragma unroll
    for (int dt = 0; dt < 4; dt++)
#pragma unroll
        for (int r = 0; r < 4; r++)
            att[(size_t)(b * SEQ + q0 + w * 16 + quad * 4 + r) * HID + hoff +
                dt * 16 + c] = f2bf(acc_o[dt][r] * zp[r]);

    if (c == 0) {
        const size_t zb = (size_t)(b * NHEAD + h) * SEQ + q0 + w * 16 + quad * 4;
#pragma unroll
        for (int r = 0; r < 4; r++) zinv_out[zb + r] = zp[r];
    }
}

// ---------------------------------------------------------------------------
// Pass 2 (MFMA): 128 k-cols/block, 8 thin waves, reg-dbuf Q staging; K
// staging overlays steady Qs/zs. XCD-swizzled. atomicAdd over heads.
// ---------------------------------------------------------------------------
__global__ __launch_bounds__(512) void colsum_mfma_kernel(
    const unsigned short* __restrict__ qb, const unsigned short* __restrict__ kb,
    const unsigned char* __restrict__ mask, const float* __restrict__ zinv,
    float* __restrict__ colsum)
{
    const int n = blockIdx.x;
    const int xcd = n & 7, t = n >> 3;
    const int g = xcd + 8 * (t >> 4);
    const int h = g & 15, b = g >> 4;
    const int k0 = (t & 15) * 128;

    const int tid = threadIdx.x;
    const int w = tid >> 6, lane = tid & 63;
    const int c = lane & 15, quad = lane >> 4;

    __shared__ unsigned short SM[9216];           // 18432 B
    unsigned short* Qs = SM;                      // steady [64][72]
    float* zs = (float*)(SM + 4608);              // [64]
    unsigned short* Kst = SM;                     // staging alias [128][72]

    const size_t hoff = (size_t)h * DHEAD;
#pragma unroll
    for (int it = 0; it < 2; it++) {
        const int gg = it * 512 + tid;
        const int r = gg >> 3, c8 = (gg & 7) << 3;
        *(uint4*)&Kst[r * 72 + c8] =
            *(const uint4*)&kb[(size_t)(b * SEQ + k0 + r) * HID + hoff + c8];
    }
    float mb[4];
#pragma unroll
    for (int r = 0; r < 4; r++)
        mb[r] = mask[(size_t)b * SEQ + k0 + w * 16 + quad * 4 + r] ? -1e9f : 0.f;
    __syncthreads();
    const short8 ak0 = *(const short8*)&Kst[(w * 16 + c) * 72 + quad * 8];
    const short8 ak1 = *(const short8*)&Kst[(w * 16 + c) * 72 + 32 + quad * 8];

    float cs[4] = {0.f, 0.f, 0.f, 0.f};
    const size_t zbase = (size_t)(b * NHEAD + h) * SEQ;

    const int sr = tid >> 3, sc8 = (tid & 7) << 3;
    uint4 qreg = *(const uint4*)&qb[(size_t)(b * SEQ + sr) * HID + hoff + sc8];
    float zreg = 0.f;
    if (tid < 64) zreg = zinv[zbase + tid];

    for (int qc = 0; qc < SEQ; qc += 64) {
        __syncthreads();
        *(uint4*)&Qs[sr * 72 + sc8] = qreg;
        if (tid < 64) zs[tid] = zreg;
        __syncthreads();
        if (qc + 64 < SEQ) {
            qreg = *(const uint4*)&qb[(size_t)(b * SEQ + qc + 64 + sr) * HID + hoff + sc8];
            if (tid < 64) zreg = zinv[zbase + qc + 64 + tid];
        }

#pragma unroll
        for (int qt = 0; qt < 4; qt++) {
            const short8 bq0 = *(const short8*)&Qs[(qt * 16 + c) * 72 + quad * 8];
            const short8 bq1 = *(const short8*)&Qs[(qt * 16 + c) * 72 + 32 + quad * 8];
            floatx4 s = (floatx4){0.f, 0.f, 0.f, 0.f};
            s = MFMA16(ak0, bq0, s);
            s = MFMA16(ak1, bq1, s);
            const float zi = zs[qt * 16 + c];
#pragma unroll
            for (int r = 0; r < 4; r++)
                cs[r] += EXP2F(fmaf(s[r], SCALE_LOG2E, mb[r])) * zi;
        }
    }

#pragma unroll
    for (int r = 0; r < 4; r++) {
        float v = cs[r];
        v += __shfl_xor(v, 1, 64); v += __shfl_xor(v, 2, 64);
        v += __shfl_xor(v, 4, 64); v += __shfl_xor(v, 8, 64);
        if (c == 0)
            atomicAdd(&colsum[(size_t)b * SEQ + k0 + w * 16 + quad * 4 + r], v);
    }
}

// ---------------------------------------------------------------------------
extern "C" void kernel_launch(void* const* d_in, const int* in_sizes, int n_in,
                              void* d_out, int out_size, void* d_ws, size_t ws_size,
                              hipStream_t stream)
{
    const float* v  = (const float*)d_in[0];
    const float* k  = (const float*)d_in[1];
    const float* q  = (const float*)d_in[2];
    const unsigned char* mask = (const unsigned char*)d_in[3];
    const float* Wv = (const float*)d_in[4];
    const float* bv = (const float*)d_in[5];
    const float* Wk = (const float*)d_in[6];
    const float* bk = (const float*)d_in[7];
    const float* Wq = (const float*)d_in[8];
    const float* bq = (const float*)d_in[9];
    const float* Wt = (const float*)d_in[10];
    const float* bt = (const float*)d_in[11];
    const float* Wm = (const float*)d_in[12];
    const float* bm = (const float*)d_in[13];
    float* out = (float*)d_out;

    const size_t NE = (size_t)MROWS * HID;
    const size_t WE = (size_t)HID * HID;
    unsigned short* qa   = (unsigned short*)d_ws;
    unsigned short* ka   = qa  + NE;
    unsigned short* va   = ka  + NE;
    unsigned short* qp   = va  + NE;
    unsigned short* kp   = qp  + NE;
    unsigned short* vtb  = kp  + NE;
    unsigned short* WqT  = vtb + NE;
    unsigned short* WkT  = WqT + WE;
    unsigned short* WvT  = WkT + WE;
    unsigned short* WmT  = WvT + WE;
    float* thr    = (float*)(WmT + WE);
    float* zinv   = thr  + MROWS;
    float* colsum = zinv + (size_t)BATCH * NHEAD * SEQ;
    // attb aliases qa: qa is only read by proj3 (z=0), dead before flash runs
    unsigned short* attb = qa;

    wtrans_kernel<<<dim3(HID / 64, HID / 64, 4), 256, 0, stream>>>(
        Wq, Wk, Wv, Wm, WqT, WkT, WvT, WmT);

    cvt_bf16_kernel<<<dim3((unsigned)(NE / (256 * 8)), 3), 256, 0, stream>>>(
        q, k, v, qa, ka, va);

    proj3_mfma_kernel<<<dim3(MROWS / 128, HID / 128, 3), 256, 0, stream>>>(
        qa, ka, va, WqT, WkT, WvT, bq, bk, bv, qp, kp, vtb);

    threshold_kernel<<<MROWS / 4, 256, 0, stream>>>(qp, kp, Wt, bt, thr, colsum);

    flash_mfma_kernel<<<BATCH * NHEAD * (SEQ / 128), 512, 0, stream>>>(
        qp, kp, vtb, mask, attb, zinv);

    colsum_mfma_kernel<<<BATCH * NHEAD * (SEQ / 128), 512, 0, stream>>>(
        qp, kp, mask, zinv, colsum);

    gemm_gate_kernel<<<dim3(MROWS / 128, HID / 128), 256, 0, stream>>>(
        attb, WmT, bm, colsum, thr, out);
}

// Round 9
// 287.492 us; speedup vs baseline: 1.2438x; 1.0012x over previous
//
#include <hip/hip_runtime.h>
#include <math.h>

#define BATCH 2
#define SEQ   2048
#define HID   1024
#define NHEAD 16
#define DHEAD 64
#define MROWS (BATCH*SEQ)      // 4096
#define SCALE_LOG2E 0.1803368801111244f   // 0.125 * log2(e)

typedef __attribute__((ext_vector_type(8))) short short8;
typedef __attribute__((ext_vector_type(4))) short short4v;
typedef __attribute__((ext_vector_type(4))) float floatx4;
#define MFMA16(a,b,c) __builtin_amdgcn_mfma_f32_16x16x32_bf16(a,b,c,0,0,0)

extern "C" __device__ float __ocml_native_exp2_f32(float);
#define EXP2F(x) __ocml_native_exp2_f32(x)

// global -> LDS direct DMA, 16B per lane. LDS dest is wave-uniform base +
// lane*16 (no per-lane scatter, no padding allowed in the staged tile).
#define GLOBAL_TO_LDS16(g, l)                                                  \
    __builtin_amdgcn_global_load_lds(                                          \
        (const __attribute__((address_space(1))) void*)(g),                    \
        (__attribute__((address_space(3))) void*)(l), 16, 0, 0)

__device__ __forceinline__ unsigned short f2bf(float x) {   // round-half-up
    union { float f; unsigned u; } v; v.f = x;
    return (unsigned short)((v.u + 0x8000u) >> 16);
}
__device__ __forceinline__ float bf2f(unsigned short s) {
    union { unsigned u; float f; } v; v.u = ((unsigned)s) << 16;
    return v.f;
}
__device__ __forceinline__ unsigned pack_bf16(float lo, float hi) {
    union { float f; unsigned u; } a, b; a.f = lo; b.f = hi;
    return __builtin_amdgcn_perm(b.u + 0x8000u, a.u + 0x8000u, 0x07060302u);
}

// ---------------------------------------------------------------------------
// fp32 -> bf16 bulk convert; blockIdx.y selects among 3 tensors
// ---------------------------------------------------------------------------
__global__ __launch_bounds__(256) void cvt_bf16_kernel(
    const float* __restrict__ i0, const float* __restrict__ i1,
    const float* __restrict__ i2,
    unsigned short* __restrict__ o0, unsigned short* __restrict__ o1,
    unsigned short* __restrict__ o2)
{
    const float* in; unsigned short* out;
    switch (blockIdx.y) {
        case 0:  in = i0; out = o0; break;
        case 1:  in = i1; out = o1; break;
        default: in = i2; out = o2; break;
    }
    const size_t i = ((size_t)blockIdx.x * 256 + threadIdx.x) * 8;
    const float4 a = *(const float4*)&in[i];
    const float4 b = *(const float4*)&in[i + 4];
    uint4 u;
    u.x = pack_bf16(a.x, a.y); u.y = pack_bf16(a.z, a.w);
    u.z = pack_bf16(b.x, b.y); u.w = pack_bf16(b.z, b.w);
    *(uint4*)&out[i] = u;
}

// ---------------------------------------------------------------------------
// 4x W[K][N] fp32 -> Wt[N][K] bf16 in one launch (blockIdx.z selects W)
// ---------------------------------------------------------------------------
__global__ __launch_bounds__(256) void wtrans_kernel(
    const float* __restrict__ W0, const float* __restrict__ W1,
    const float* __restrict__ W2, const float* __restrict__ W3,
    unsigned short* __restrict__ T0, unsigned short* __restrict__ T1,
    unsigned short* __restrict__ T2, unsigned short* __restrict__ T3)
{
    const float* W; unsigned short* Wt;
    switch (blockIdx.z) {
        case 0: W = W0; Wt = T0; break;
        case 1: W = W1; Wt = T1; break;
        case 2: W = W2; Wt = T2; break;
        default: W = W3; Wt = T3; break;
    }
    __shared__ float T[64][68];
    const int tid = threadIdx.x;
    const int k0 = blockIdx.x * 64, n0 = blockIdx.y * 64;
#pragma unroll
    for (int it = 0; it < 4; it++) {
        const int id = it * 256 + tid;
        const int r = id >> 4, c4 = (id & 15) << 2;
        *(float4*)&T[r][c4] = *(const float4*)&W[(size_t)(k0 + r) * HID + n0 + c4];
    }
    __syncthreads();
#pragma unroll
    for (int it = 0; it < 2; it++) {
        const int id = it * 256 + tid;
        const int n = id >> 3, k8 = (id & 7) << 3;
        uint4 u;
        u.x = pack_bf16(T[k8 + 0][n], T[k8 + 1][n]);
        u.y = pack_bf16(T[k8 + 2][n], T[k8 + 3][n]);
        u.z = pack_bf16(T[k8 + 4][n], T[k8 + 5][n]);
        u.w = pack_bf16(T[k8 + 6][n], T[k8 + 7][n]);
        *(uint4*)&Wt[(size_t)(n0 + n) * HID + k0 + k8] = u;
    }
}

// ---------------------------------------------------------------------------
// Fused Q/K/V projection GEMM via global_load_lds (width 16) with XOR-swizzled
// global gather: LDS slot [r][g] holds global col-group g^(r&7); frag reads
// XOR the same term (2-way bank spread = free). Unpadded [128][64] tiles.
// z<2 -> row-major bf16 out; z==2 -> vt[b][h][d][seq] directly.
// ---------------------------------------------------------------------------
__global__ __launch_bounds__(256) void proj3_mfma_kernel(
    const unsigned short* __restrict__ A0, const unsigned short* __restrict__ A1,
    const unsigned short* __restrict__ A2,
    const unsigned short* __restrict__ B0, const unsigned short* __restrict__ B1,
    const unsigned short* __restrict__ B2,
    const float* __restrict__ bi0, const float* __restrict__ bi1,
    const float* __restrict__ bi2,
    unsigned short* __restrict__ C0, unsigned short* __restrict__ C1,
    unsigned short* __restrict__ vt)
{
    const unsigned short *Ab, *Bt; const float* bias;
    switch (blockIdx.z) {
        case 0:  Ab = A0; Bt = B0; bias = bi0; break;
        case 1:  Ab = A1; Bt = B1; bias = bi1; break;
        default: Ab = A2; Bt = B2; bias = bi2; break;
    }
    __shared__ unsigned short As[128 * 64];
    __shared__ unsigned short Bs[128 * 64];
    const int tid = threadIdx.x;
    const int w = tid >> 6, lane = tid & 63;
    const int c = lane & 15, quad = lane >> 4;
    const int m0 = blockIdx.x * 128, n0 = blockIdx.y * 128;
    const int wm = (w >> 1) * 64, wn = (w & 1) * 64;
    const int xr = c & 7;   // frag-read swizzle term

    floatx4 acc[4][4];
#pragma unroll
    for (int i = 0; i < 4; i++)
#pragma unroll
        for (int j = 0; j < 4; j++) acc[i][j] = (floatx4){0.f, 0.f, 0.f, 0.f};

    for (int kc = 0; kc < HID; kc += 64) {
        __syncthreads();
#pragma unroll
        for (int it = 0; it < 4; it++) {
            const int id = it * 256 + tid;
            const int r = id >> 3;
            const int gsw = ((id & 7) ^ (r & 7)) << 3;
            GLOBAL_TO_LDS16(&Ab[(size_t)(m0 + r) * HID + kc + gsw], &As[id << 3]);
            GLOBAL_TO_LDS16(&Bt[(size_t)(n0 + r) * HID + kc + gsw], &Bs[id << 3]);
        }
        __syncthreads();
#pragma unroll
        for (int kk = 0; kk < 2; kk++) {
            short8 af[4], bf[4];
#pragma unroll
            for (int mt = 0; mt < 4; mt++)
                af[mt] = *(const short8*)
                    &As[((wm + mt * 16 + c) << 6) + (((kk * 4 + quad) ^ xr) << 3)];
#pragma unroll
            for (int nt = 0; nt < 4; nt++)
                bf[nt] = *(const short8*)
                    &Bs[((wn + nt * 16 + c) << 6) + (((kk * 4 + quad) ^ xr) << 3)];
#pragma unroll
            for (int mt = 0; mt < 4; mt++)
#pragma unroll
                for (int nt = 0; nt < 4; nt++)
                    acc[mt][nt] = MFMA16(af[mt], bf[nt], acc[mt][nt]);
        }
    }

    if (blockIdx.z < 2) {
        unsigned short* Cb = blockIdx.z == 0 ? C0 : C1;
#pragma unroll
        for (int nt = 0; nt < 4; nt++) {
            const int n = n0 + wn + nt * 16 + c;
            const float bb = bias[n];
#pragma unroll
            for (int mt = 0; mt < 4; mt++) {
                const int m = m0 + wm + mt * 16 + quad * 4;
#pragma unroll
                for (int r = 0; r < 4; r++)
                    Cb[(size_t)(m + r) * HID + n] = f2bf(acc[mt][nt][r] + bb);
            }
        }
    } else {
#pragma unroll
        for (int nt = 0; nt < 4; nt++) {
            const int n = n0 + wn + nt * 16 + c;
            const float bb = bias[n];
            const int h = n >> 6, d = n & 63;
#pragma unroll
            for (int mt = 0; mt < 4; mt++) {
                const int m = m0 + wm + mt * 16 + quad * 4;
                const int b = m >> 11, l = m & 2047;
                ushort4 u;
                u.x = f2bf(acc[mt][nt][0] + bb);
                u.y = f2bf(acc[mt][nt][1] + bb);
                u.z = f2bf(acc[mt][nt][2] + bb);
                u.w = f2bf(acc[mt][nt][3] + bb);
                *(ushort4*)&vt[((size_t)(b * NHEAD + h) * DHEAD + d) * SEQ + l] = u;
            }
        }
    }
}

// ---------------------------------------------------------------------------
// Final GEMM, same global_load_lds structure; gate applied in the EPILOGUE
// (gating A rows == gating output rows: out[m] = gate ? acc+b : b).
// ---------------------------------------------------------------------------
__global__ __launch_bounds__(256) void gemm_gate_kernel(
    const unsigned short* __restrict__ Ab, const unsigned short* __restrict__ Bt,
    const float* __restrict__ bias,
    const float* __restrict__ gate_cs, const float* __restrict__ gate_th,
    float* __restrict__ Cf)
{
    __shared__ unsigned short As[128 * 64];
    __shared__ unsigned short Bs[128 * 64];
    const int tid = threadIdx.x;
    const int w = tid >> 6, lane = tid & 63;
    const int c = lane & 15, quad = lane >> 4;
    const int m0 = blockIdx.x * 128, n0 = blockIdx.y * 128;
    const int wm = (w >> 1) * 64, wn = (w & 1) * 64;
    const int xr = c & 7;

    floatx4 acc[4][4];
#pragma unroll
    for (int i = 0; i < 4; i++)
#pragma unroll
        for (int j = 0; j < 4; j++) acc[i][j] = (floatx4){0.f, 0.f, 0.f, 0.f};

    for (int kc = 0; kc < HID; kc += 64) {
        __syncthreads();
#pragma unroll
        for (int it = 0; it < 4; it++) {
            const int id = it * 256 + tid;
            const int r = id >> 3;
            const int gsw = ((id & 7) ^ (r & 7)) << 3;
            GLOBAL_TO_LDS16(&Ab[(size_t)(m0 + r) * HID + kc + gsw], &As[id << 3]);
            GLOBAL_TO_LDS16(&Bt[(size_t)(n0 + r) * HID + kc + gsw], &Bs[id << 3]);
        }
        __syncthreads();
#pragma unroll
        for (int kk = 0; kk < 2; kk++) {
            short8 af[4], bf[4];
#pragma unroll
            for (int mt = 0; mt < 4; mt++)
                af[mt] = *(const short8*)
                    &As[((wm + mt * 16 + c) << 6) + (((kk * 4 + quad) ^ xr) << 3)];
#pragma unroll
            for (int nt = 0; nt < 4; nt++)
                bf[nt] = *(const short8*)
                    &Bs[((wn + nt * 16 + c) << 6) + (((kk * 4 + quad) ^ xr) << 3)];
#pragma unroll
            for (int mt = 0; mt < 4; mt++)
#pragma unroll
                for (int nt = 0; nt < 4; nt++)
                    acc[mt][nt] = MFMA16(af[mt], bf[nt], acc[mt][nt]);
        }
    }

    float gmul[4][4];   // [mt][r] gate for row m
#pragma unroll
    for (int mt = 0; mt < 4; mt++)
#pragma unroll
        for (int r = 0; r < 4; r++) {
            const int m = m0 + wm + mt * 16 + quad * 4 + r;
            gmul[mt][r] = (gate_cs[m] - gate_th[m]) > 0.f ? 1.f : 0.f;
        }

#pragma unroll
    for (int nt = 0; nt < 4; nt++) {
        const int n = n0 + wn + nt * 16 + c;
        const float bb = bias[n];
#pragma unroll
        for (int mt = 0; mt < 4; mt++) {
            const int m = m0 + wm + mt * 16 + quad * 4;
#pragma unroll
            for (int r = 0; r < 4; r++)
                Cf[(size_t)(m + r) * HID + n] = fmaf(acc[mt][nt][r], gmul[mt][r], bb);
        }
    }
}

// ---------------------------------------------------------------------------
// threshold[row] = sum_h qb*kb*Wt + bt; also zeroes colsum[row]
// ---------------------------------------------------------------------------
__global__ __launch_bounds__(256) void threshold_kernel(
    const unsigned short* __restrict__ qb, const unsigned short* __restrict__ kb,
    const float* __restrict__ Wt, const float* __restrict__ bt,
    float* __restrict__ thr, float* __restrict__ colsum)
{
    const int w = threadIdx.x >> 6, lane = threadIdx.x & 63;
    const int row = blockIdx.x * 4 + w;
    const unsigned short* qr = qb + (size_t)row * HID;
    const unsigned short* kr = kb + (size_t)row * HID;
    float s = 0.f;
#pragma unroll
    for (int ii = 0; ii < 2; ii++) {
        const int base = ii * 512 + lane * 8;
        const ushort4 q0 = *(const ushort4*)&qr[base];
        const ushort4 q1 = *(const ushort4*)&qr[base + 4];
        const ushort4 k0 = *(const ushort4*)&kr[base];
        const ushort4 k1 = *(const ushort4*)&kr[base + 4];
        const float4 w0 = *(const float4*)&Wt[base];
        const float4 w1 = *(const float4*)&Wt[base + 4];
        s += bf2f(q0.x) * bf2f(k0.x) * w0.x + bf2f(q0.y) * bf2f(k0.y) * w0.y +
             bf2f(q0.z) * bf2f(k0.z) * w0.z + bf2f(q0.w) * bf2f(k0.w) * w0.w +
             bf2f(q1.x) * bf2f(k1.x) * w1.x + bf2f(q1.y) * bf2f(k1.y) * w1.y +
             bf2f(q1.z) * bf2f(k1.z) * w1.z + bf2f(q1.w) * bf2f(k1.w) * w1.w;
    }
#pragma unroll
    for (int off = 32; off > 0; off >>= 1) s += __shfl_xor(s, off, 64);
    if (lane == 0) { thr[row] = s + bt[0]; colsum[row] = 0.f; }
}

// ---------------------------------------------------------------------------
// Pass 1 (MFMA): 128 q-rows/block, 8 thin waves (16 q each). Reg-dbuf K/V
// staging; Qs staging overlays the steady Ks/Vs/Ps region. XCD-swizzled.
// ---------------------------------------------------------------------------
__global__ __launch_bounds__(512) void flash_mfma_kernel(
    const unsigned short* __restrict__ qb, const unsigned short* __restrict__ kb,
    const unsigned short* __restrict__ vt, const unsigned char* __restrict__ mask,
    unsigned short* __restrict__ att, float* __restrict__ zinv_out)
{
    const int n = blockIdx.x;
    const int xcd = n & 7, t = n >> 3;
    const int g = xcd + 8 * (t >> 4);
    const int qblk = t & 15;
    const int h = g & 15, b = g >> 4;
    const int q0 = qblk * 128;

    const int tid = threadIdx.x;
    const int w = tid >> 6, lane = tid & 63;
    const int c = lane & 15, quad = lane >> 4;

    __shared__ unsigned short SM[18048];          // 36096 B
    unsigned short* Ks = SM;                      // [64][72]
    unsigned short* Vs = SM + 4608;               // [64][72]  Vs[d][j]
    unsigned short* Ps = SM + 9216;               // [8][16][68]
    float* mbf = (float*)(SM + 17920);            // [64]
    unsigned short* Qs = SM;                      // staging alias [128][72]

    const size_t hoff = (size_t)h * DHEAD;
#pragma unroll
    for (int it = 0; it < 2; it++) {
        const int gg = it * 512 + tid;
        const int r = gg >> 3, c8 = (gg & 7) << 3;
        *(uint4*)&Qs[r * 72 + c8] =
            *(const uint4*)&qb[(size_t)(b * SEQ + q0 + r) * HID + hoff + c8];
    }
    __syncthreads();
    const short8 aq0 = *(const short8*)&Qs[(w * 16 + c) * 72 + quad * 8];
    const short8 aq1 = *(const short8*)&Qs[(w * 16 + c) * 72 + 32 + quad * 8];

    floatx4 acc_o[4];
#pragma unroll
    for (int dt = 0; dt < 4; dt++) acc_o[dt] = (floatx4){0.f, 0.f, 0.f, 0.f};
    float zp[4] = {0.f, 0.f, 0.f, 0.f};
    const size_t vtbase = (size_t)(b * NHEAD + h) * DHEAD * SEQ;

    const int sr = tid >> 3, sc8 = (tid & 7) << 3;
    uint4 kreg = *(const uint4*)&kb[(size_t)(b * SEQ + sr) * HID + hoff + sc8];
    uint4 vreg = *(const uint4*)&vt[vtbase + (size_t)sr * SEQ + sc8];
    float mreg = 0.f;
    if (tid < 64) mreg = mask[(size_t)b * SEQ + tid] ? -1e9f : 0.f;

    for (int kc = 0; kc < SEQ; kc += 64) {
        __syncthreads();
        *(uint4*)&Ks[sr * 72 + sc8] = kreg;
        *(uint4*)&Vs[sr * 72 + sc8] = vreg;
        if (tid < 64) mbf[tid] = mreg;
        __syncthreads();
        if (kc + 64 < SEQ) {
            kreg = *(const uint4*)&kb[(size_t)(b * SEQ + kc + 64 + sr) * HID + hoff + sc8];
            vreg = *(const uint4*)&vt[vtbase + (size_t)sr * SEQ + kc + 64 + sc8];
            if (tid < 64) mreg = mask[(size_t)b * SEQ + kc + 64 + tid] ? -1e9f : 0.f;
        }

#pragma unroll
        for (int nt = 0; nt < 4; nt++) {
            const short8 bk0 = *(const short8*)&Ks[(nt * 16 + c) * 72 + quad * 8];
            const short8 bk1 = *(const short8*)&Ks[(nt * 16 + c) * 72 + 32 + quad * 8];
            floatx4 s = (floatx4){0.f, 0.f, 0.f, 0.f};
            s = MFMA16(aq0, bk0, s);
            s = MFMA16(aq1, bk1, s);
            const float mb = mbf[nt * 16 + c];
#pragma unroll
            for (int r = 0; r < 4; r++) {
                const float p = EXP2F(fmaf(s[r], SCALE_LOG2E, mb));
                zp[r] += p;
                Ps[(w * 16 + quad * 4 + r) * 68 + nt * 16 + c] = f2bf(p);
            }
        }

        const unsigned short* pr = &Ps[(w * 16 + c) * 68];
        short4v p00 = *(const short4v*)&pr[quad * 8];
        short4v p01 = *(const short4v*)&pr[quad * 8 + 4];
        short4v p10 = *(const short4v*)&pr[32 + quad * 8];
        short4v p11 = *(const short4v*)&pr[32 + quad * 8 + 4];
        const short8 ap0 = __builtin_shufflevector(p00, p01, 0, 1, 2, 3, 4, 5, 6, 7);
        const short8 ap1 = __builtin_shufflevector(p10, p11, 0, 1, 2, 3, 4, 5, 6, 7);
#pragma unroll
        for (int dt = 0; dt < 4; dt++) {
            const short8 bv0 = *(const short8*)&Vs[(dt * 16 + c) * 72 + quad * 8];
            const short8 bv1 = *(const short8*)&Vs[(dt * 16 + c) * 72 + 32 + quad * 8];
            acc_o[dt] = MFMA16(ap0, bv0, acc_o[dt]);
            acc_o[dt] = MFMA16(ap1, bv1, acc_o[dt]);
        }
    }

#pragma unroll
    for (int r = 0; r < 4; r++) {
        float z = zp[r];
        z += __shfl_xor(z, 1, 64); z += __shfl_xor(z, 2, 64);
        z += __shfl_xor(z, 4, 64); z += __shfl_xor(z, 8, 64);
        zp[r] = 1.0f / (z + 1e-30f);
    }

#pragma unroll
    for (int dt = 0; dt < 4; dt++)
#pragma unroll
        for (int r = 0; r < 4; r++)
            att[(size_t)(b * SEQ + q0 + w * 16 + quad * 4 + r) * HID + hoff +
                dt * 16 + c] = f2bf(acc_o[dt][r] * zp[r]);

    if (c == 0) {
        const size_t zb = (size_t)(b * NHEAD + h) * SEQ + q0 + w * 16 + quad * 4;
#pragma unroll
        for (int r = 0; r < 4; r++) zinv_out[zb + r] = zp[r];
    }
}

// ---------------------------------------------------------------------------
// Pass 2 (MFMA): 128 k-cols/block, 8 thin waves, reg-dbuf Q staging; K
// staging overlays steady Qs/zs. XCD-swizzled. atomicAdd over heads.
// ---------------------------------------------------------------------------
__global__ __launch_bounds__(512) void colsum_mfma_kernel(
    const unsigned short* __restrict__ qb, const unsigned short* __restrict__ kb,
    const unsigned char* __restrict__ mask, const float* __restrict__ zinv,
    float* __restrict__ colsum)
{
    const int n = blockIdx.x;
    const int xcd = n & 7, t = n >> 3;
    const int g = xcd + 8 * (t >> 4);
    const int h = g & 15, b = g >> 4;
    const int k0 = (t & 15) * 128;

    const int tid = threadIdx.x;
    const int w = tid >> 6, lane = tid & 63;
    const int c = lane & 15, quad = lane >> 4;

    __shared__ unsigned short SM[9216];           // 18432 B
    unsigned short* Qs = SM;                      // steady [64][72]
    float* zs = (float*)(SM + 4608);              // [64]
    unsigned short* Kst = SM;                     // staging alias [128][72]

    const size_t hoff = (size_t)h * DHEAD;
#pragma unroll
    for (int it = 0; it < 2; it++) {
        const int gg = it * 512 + tid;
        const int r = gg >> 3, c8 = (gg & 7) << 3;
        *(uint4*)&Kst[r * 72 + c8] =
            *(const uint4*)&kb[(size_t)(b * SEQ + k0 + r) * HID + hoff + c8];
    }
    float mb[4];
#pragma unroll
    for (int r = 0; r < 4; r++)
        mb[r] = mask[(size_t)b * SEQ + k0 + w * 16 + quad * 4 + r] ? -1e9f : 0.f;
    __syncthreads();
    const short8 ak0 = *(const short8*)&Kst[(w * 16 + c) * 72 + quad * 8];
    const short8 ak1 = *(const short8*)&Kst[(w * 16 + c) * 72 + 32 + quad * 8];

    float cs[4] = {0.f, 0.f, 0.f, 0.f};
    const size_t zbase = (size_t)(b * NHEAD + h) * SEQ;

    const int sr = tid >> 3, sc8 = (tid & 7) << 3;
    uint4 qreg = *(const uint4*)&qb[(size_t)(b * SEQ + sr) * HID + hoff + sc8];
    float zreg = 0.f;
    if (tid < 64) zreg = zinv[zbase + tid];

    for (int qc = 0; qc < SEQ; qc += 64) {
        __syncthreads();
        *(uint4*)&Qs[sr * 72 + sc8] = qreg;
        if (tid < 64) zs[tid] = zreg;
        __syncthreads();
        if (qc + 64 < SEQ) {
            qreg = *(const uint4*)&qb[(size_t)(b * SEQ + qc + 64 + sr) * HID + hoff + sc8];
            if (tid < 64) zreg = zinv[zbase + qc + 64 + tid];
        }

#pragma unroll
        for (int qt = 0; qt < 4; qt++) {
            const short8 bq0 = *(const short8*)&Qs[(qt * 16 + c) * 72 + quad * 8];
            const short8 bq1 = *(const short8*)&Qs[(qt * 16 + c) * 72 + 32 + quad * 8];
            floatx4 s = (floatx4){0.f, 0.f, 0.f, 0.f};
            s = MFMA16(ak0, bq0, s);
            s = MFMA16(ak1, bq1, s);
            const float zi = zs[qt * 16 + c];
#pragma unroll
            for (int r = 0; r < 4; r++)
                cs[r] += EXP2F(fmaf(s[r], SCALE_LOG2E, mb[r])) * zi;
        }
    }

#pragma unroll
    for (int r = 0; r < 4; r++) {
        float v = cs[r];
        v += __shfl_xor(v, 1, 64); v += __shfl_xor(v, 2, 64);
        v += __shfl_xor(v, 4, 64); v += __shfl_xor(v, 8, 64);
        if (c == 0)
            atomicAdd(&colsum[(size_t)b * SEQ + k0 + w * 16 + quad * 4 + r], v);
    }
}

// ---------------------------------------------------------------------------
extern "C" void kernel_launch(void* const* d_in, const int* in_sizes, int n_in,
                              void* d_out, int out_size, void* d_ws, size_t ws_size,
                              hipStream_t stream)
{
    const float* v  = (const float*)d_in[0];
    const float* k  = (const float*)d_in[1];
    const float* q  = (const float*)d_in[2];
    const unsigned char* mask = (const unsigned char*)d_in[3];
    const float* Wv = (const float*)d_in[4];
    const float* bv = (const float*)d_in[5];
    const float* Wk = (const float*)d_in[6];
    const float* bk = (const float*)d_in[7];
    const float* Wq = (const float*)d_in[8];
    const float* bq = (const float*)d_in[9];
    const float* Wt = (const float*)d_in[10];
    const float* bt = (const float*)d_in[11];
    const float* Wm = (const float*)d_in[12];
    const float* bm = (const float*)d_in[13];
    float* out = (float*)d_out;

    const size_t NE = (size_t)MROWS * HID;
    const size_t WE = (size_t)HID * HID;
    unsigned short* qa   = (unsigned short*)d_ws;
    unsigned short* ka   = qa  + NE;
    unsigned short* va   = ka  + NE;
    unsigned short* qp   = va  + NE;
    unsigned short* kp   = qp  + NE;
    unsigned short* vtb  = kp  + NE;
    unsigned short* WqT  = vtb + NE;
    unsigned short* WkT  = WqT + WE;
    unsigned short* WvT  = WkT + WE;
    unsigned short* WmT  = WvT + WE;
    float* thr    = (float*)(WmT + WE);
    float* zinv   = thr  + MROWS;
    float* colsum = zinv + (size_t)BATCH * NHEAD * SEQ;
    // attb aliases qa: qa is only read by proj3 (z=0), dead before flash runs
    unsigned short* attb = qa;

    wtrans_kernel<<<dim3(HID / 64, HID / 64, 4), 256, 0, stream>>>(
        Wq, Wk, Wv, Wm, WqT, WkT, WvT, WmT);

    cvt_bf16_kernel<<<dim3((unsigned)(NE / (256 * 8)), 3), 256, 0, stream>>>(
        q, k, v, qa, ka, va);

    proj3_mfma_kernel<<<dim3(MROWS / 128, HID / 128, 3), 256, 0, stream>>>(
        qa, ka, va, WqT, WkT, WvT, bq, bk, bv, qp, kp, vtb);

    threshold_kernel<<<MROWS / 4, 256, 0, stream>>>(qp, kp, Wt, bt, thr, colsum);

    flash_mfma_kernel<<<BATCH * NHEAD * (SEQ / 128), 512, 0, stream>>>(
        qp, kp, vtb, mask, attb, zinv);

    colsum_mfma_kernel<<<BATCH * NHEAD * (SEQ / 128), 512, 0, stream>>>(
        qp, kp, mask, zinv, colsum);

    gemm_gate_kernel<<<dim3(MROWS / 128, HID / 128), 256, 0, stream>>>(
        attb, WmT, bm, colsum, thr, out);
}

// Round 10
// 280.870 us; speedup vs baseline: 1.2731x; 1.0236x over previous
//
#include <hip/hip_runtime.h>
#include <math.h>

#define BATCH 2
#define SEQ   2048
#define HID   1024
#define NHEAD 16
#define DHEAD 64
#define MROWS (BATCH*SEQ)      // 4096
#define SCALE_LOG2E 0.1803368801111244f   // 0.125 * log2(e)

typedef __attribute__((ext_vector_type(8))) short short8;
typedef __attribute__((ext_vector_type(4))) short short4v;
typedef __attribute__((ext_vector_type(4))) float floatx4;
#define MFMA16(a,b,c) __builtin_amdgcn_mfma_f32_16x16x32_bf16(a,b,c,0,0,0)

extern "C" __device__ float __ocml_native_exp2_f32(float);
#define EXP2F(x) __ocml_native_exp2_f32(x)

// global -> LDS direct DMA, 16B per lane (wave-uniform base + lane*16)
#define GLOBAL_TO_LDS16(g, l)                                                  \
    __builtin_amdgcn_global_load_lds(                                          \
        (const __attribute__((address_space(1))) void*)(g),                    \
        (__attribute__((address_space(3))) void*)(l), 16, 0, 0)

__device__ __forceinline__ unsigned short f2bf(float x) {   // round-half-up
    union { float f; unsigned u; } v; v.f = x;
    return (unsigned short)((v.u + 0x8000u) >> 16);
}
__device__ __forceinline__ float bf2f(unsigned short s) {
    union { unsigned u; float f; } v; v.u = ((unsigned)s) << 16;
    return v.f;
}
__device__ __forceinline__ unsigned pack_bf16(float lo, float hi) {
    union { float f; unsigned u; } a, b; a.f = lo; b.f = hi;
    return __builtin_amdgcn_perm(b.u + 0x8000u, a.u + 0x8000u, 0x07060302u);
}

// ---------------------------------------------------------------------------
// PREP (one launch): blocks [0,6144) cvt fp32->bf16 of q/k/v;
// [6144,7168) the 4 weight transposes; [7168,7170) zero colsum.
// ---------------------------------------------------------------------------
__global__ __launch_bounds__(256) void prep_kernel(
    const float* __restrict__ qf, const float* __restrict__ kf,
    const float* __restrict__ vf,
    unsigned short* __restrict__ qa, unsigned short* __restrict__ ka,
    unsigned short* __restrict__ va,
    const float* __restrict__ W0, const float* __restrict__ W1,
    const float* __restrict__ W2, const float* __restrict__ W3,
    unsigned short* __restrict__ T0, unsigned short* __restrict__ T1,
    unsigned short* __restrict__ T2, unsigned short* __restrict__ T3,
    float* __restrict__ colsum)
{
    __shared__ float T[64][68];
    const int bid = blockIdx.x;
    const int tid = threadIdx.x;

    if (bid < 6144) {                    // ---- cvt: 3 x 2048 blocks
        const int which = bid >> 11, pos = bid & 2047;
        const float* in; unsigned short* out;
        switch (which) {
            case 0:  in = qf; out = qa; break;
            case 1:  in = kf; out = ka; break;
            default: in = vf; out = va; break;
        }
        const size_t i = ((size_t)pos * 256 + tid) * 8;
        const float4 a = *(const float4*)&in[i];
        const float4 b = *(const float4*)&in[i + 4];
        uint4 u;
        u.x = pack_bf16(a.x, a.y); u.y = pack_bf16(a.z, a.w);
        u.z = pack_bf16(b.x, b.y); u.w = pack_bf16(b.z, b.w);
        *(uint4*)&out[i] = u;
    } else if (bid < 7168) {             // ---- wtrans: 4 x 256 tiles
        const int t = bid - 6144;
        const int z = t >> 8;
        const float* W; unsigned short* Wt;
        switch (z) {
            case 0:  W = W0; Wt = T0; break;
            case 1:  W = W1; Wt = T1; break;
            case 2:  W = W2; Wt = T2; break;
            default: W = W3; Wt = T3; break;
        }
        const int k0 = (t & 15) * 64, n0 = ((t >> 4) & 15) * 64;
#pragma unroll
        for (int it = 0; it < 4; it++) {
            const int id = it * 256 + tid;
            const int r = id >> 4, c4 = (id & 15) << 2;
            *(float4*)&T[r][c4] = *(const float4*)&W[(size_t)(k0 + r) * HID + n0 + c4];
        }
        __syncthreads();
#pragma unroll
        for (int it = 0; it < 2; it++) {
            const int id = it * 256 + tid;
            const int n = id >> 3, k8 = (id & 7) << 3;
            uint4 u;
            u.x = pack_bf16(T[k8 + 0][n], T[k8 + 1][n]);
            u.y = pack_bf16(T[k8 + 2][n], T[k8 + 3][n]);
            u.z = pack_bf16(T[k8 + 4][n], T[k8 + 5][n]);
            u.w = pack_bf16(T[k8 + 6][n], T[k8 + 7][n]);
            *(uint4*)&Wt[(size_t)(n0 + n) * HID + k0 + k8] = u;
        }
    } else {                             // ---- zero colsum: 2 blocks
        const int pos = bid - 7168;
        const size_t i = ((size_t)pos * 256 + tid) * 8;
        float4 z4; z4.x = 0.f; z4.y = 0.f; z4.z = 0.f; z4.w = 0.f;
        *(float4*)&colsum[i] = z4;
        *(float4*)&colsum[i + 4] = z4;
    }
}

// ---------------------------------------------------------------------------
// Fused Q/K/V projection GEMM via global_load_lds (width 16), XOR-swizzled
// gather. z<2 -> row-major bf16; z==2 -> vt[b][h][d][seq] directly.
// ---------------------------------------------------------------------------
__global__ __launch_bounds__(256) void proj3_mfma_kernel(
    const unsigned short* __restrict__ A0, const unsigned short* __restrict__ A1,
    const unsigned short* __restrict__ A2,
    const unsigned short* __restrict__ B0, const unsigned short* __restrict__ B1,
    const unsigned short* __restrict__ B2,
    const float* __restrict__ bi0, const float* __restrict__ bi1,
    const float* __restrict__ bi2,
    unsigned short* __restrict__ C0, unsigned short* __restrict__ C1,
    unsigned short* __restrict__ vt)
{
    const unsigned short *Ab, *Bt; const float* bias;
    switch (blockIdx.z) {
        case 0:  Ab = A0; Bt = B0; bias = bi0; break;
        case 1:  Ab = A1; Bt = B1; bias = bi1; break;
        default: Ab = A2; Bt = B2; bias = bi2; break;
    }
    __shared__ unsigned short As[128 * 64];
    __shared__ unsigned short Bs[128 * 64];
    const int tid = threadIdx.x;
    const int w = tid >> 6, lane = tid & 63;
    const int c = lane & 15, quad = lane >> 4;
    const int m0 = blockIdx.x * 128, n0 = blockIdx.y * 128;
    const int wm = (w >> 1) * 64, wn = (w & 1) * 64;
    const int xr = c & 7;

    floatx4 acc[4][4];
#pragma unroll
    for (int i = 0; i < 4; i++)
#pragma unroll
        for (int j = 0; j < 4; j++) acc[i][j] = (floatx4){0.f, 0.f, 0.f, 0.f};

    for (int kc = 0; kc < HID; kc += 64) {
        __syncthreads();
#pragma unroll
        for (int it = 0; it < 4; it++) {
            const int id = it * 256 + tid;
            const int r = id >> 3;
            const int gsw = ((id & 7) ^ (r & 7)) << 3;
            GLOBAL_TO_LDS16(&Ab[(size_t)(m0 + r) * HID + kc + gsw], &As[id << 3]);
            GLOBAL_TO_LDS16(&Bt[(size_t)(n0 + r) * HID + kc + gsw], &Bs[id << 3]);
        }
        __syncthreads();
#pragma unroll
        for (int kk = 0; kk < 2; kk++) {
            short8 af[4], bf[4];
#pragma unroll
            for (int mt = 0; mt < 4; mt++)
                af[mt] = *(const short8*)
                    &As[((wm + mt * 16 + c) << 6) + (((kk * 4 + quad) ^ xr) << 3)];
#pragma unroll
            for (int nt = 0; nt < 4; nt++)
                bf[nt] = *(const short8*)
                    &Bs[((wn + nt * 16 + c) << 6) + (((kk * 4 + quad) ^ xr) << 3)];
#pragma unroll
            for (int mt = 0; mt < 4; mt++)
#pragma unroll
                for (int nt = 0; nt < 4; nt++)
                    acc[mt][nt] = MFMA16(af[mt], bf[nt], acc[mt][nt]);
        }
    }

    if (blockIdx.z < 2) {
        unsigned short* Cb = blockIdx.z == 0 ? C0 : C1;
#pragma unroll
        for (int nt = 0; nt < 4; nt++) {
            const int n = n0 + wn + nt * 16 + c;
            const float bb = bias[n];
#pragma unroll
            for (int mt = 0; mt < 4; mt++) {
                const int m = m0 + wm + mt * 16 + quad * 4;
#pragma unroll
                for (int r = 0; r < 4; r++)
                    Cb[(size_t)(m + r) * HID + n] = f2bf(acc[mt][nt][r] + bb);
            }
        }
    } else {
#pragma unroll
        for (int nt = 0; nt < 4; nt++) {
            const int n = n0 + wn + nt * 16 + c;
            const float bb = bias[n];
            const int h = n >> 6, d = n & 63;
#pragma unroll
            for (int mt = 0; mt < 4; mt++) {
                const int m = m0 + wm + mt * 16 + quad * 4;
                const int b = m >> 11, l = m & 2047;
                ushort4 u;
                u.x = f2bf(acc[mt][nt][0] + bb);
                u.y = f2bf(acc[mt][nt][1] + bb);
                u.z = f2bf(acc[mt][nt][2] + bb);
                u.w = f2bf(acc[mt][nt][3] + bb);
                *(ushort4*)&vt[((size_t)(b * NHEAD + h) * DHEAD + d) * SEQ + l] = u;
            }
        }
    }
}

// ---------------------------------------------------------------------------
// Final GEMM; gate applied in the epilogue (out[m] = gate ? acc+b : b).
// ---------------------------------------------------------------------------
__global__ __launch_bounds__(256) void gemm_gate_kernel(
    const unsigned short* __restrict__ Ab, const unsigned short* __restrict__ Bt,
    const float* __restrict__ bias,
    const float* __restrict__ gate_cs, const float* __restrict__ gate_th,
    float* __restrict__ Cf)
{
    __shared__ unsigned short As[128 * 64];
    __shared__ unsigned short Bs[128 * 64];
    const int tid = threadIdx.x;
    const int w = tid >> 6, lane = tid & 63;
    const int c = lane & 15, quad = lane >> 4;
    const int m0 = blockIdx.x * 128, n0 = blockIdx.y * 128;
    const int wm = (w >> 1) * 64, wn = (w & 1) * 64;
    const int xr = c & 7;

    floatx4 acc[4][4];
#pragma unroll
    for (int i = 0; i < 4; i++)
#pragma unroll
        for (int j = 0; j < 4; j++) acc[i][j] = (floatx4){0.f, 0.f, 0.f, 0.f};

    for (int kc = 0; kc < HID; kc += 64) {
        __syncthreads();
#pragma unroll
        for (int it = 0; it < 4; it++) {
            const int id = it * 256 + tid;
            const int r = id >> 3;
            const int gsw = ((id & 7) ^ (r & 7)) << 3;
            GLOBAL_TO_LDS16(&Ab[(size_t)(m0 + r) * HID + kc + gsw], &As[id << 3]);
            GLOBAL_TO_LDS16(&Bt[(size_t)(n0 + r) * HID + kc + gsw], &Bs[id << 3]);
        }
        __syncthreads();
#pragma unroll
        for (int kk = 0; kk < 2; kk++) {
            short8 af[4], bf[4];
#pragma unroll
            for (int mt = 0; mt < 4; mt++)
                af[mt] = *(const short8*)
                    &As[((wm + mt * 16 + c) << 6) + (((kk * 4 + quad) ^ xr) << 3)];
#pragma unroll
            for (int nt = 0; nt < 4; nt++)
                bf[nt] = *(const short8*)
                    &Bs[((wn + nt * 16 + c) << 6) + (((kk * 4 + quad) ^ xr) << 3)];
#pragma unroll
            for (int mt = 0; mt < 4; mt++)
#pragma unroll
                for (int nt = 0; nt < 4; nt++)
                    acc[mt][nt] = MFMA16(af[mt], bf[nt], acc[mt][nt]);
        }
    }

    float gmul[4][4];
#pragma unroll
    for (int mt = 0; mt < 4; mt++)
#pragma unroll
        for (int r = 0; r < 4; r++) {
            const int m = m0 + wm + mt * 16 + quad * 4 + r;
            gmul[mt][r] = (gate_cs[m] - gate_th[m]) > 0.f ? 1.f : 0.f;
        }

#pragma unroll
    for (int nt = 0; nt < 4; nt++) {
        const int n = n0 + wn + nt * 16 + c;
        const float bb = bias[n];
#pragma unroll
        for (int mt = 0; mt < 4; mt++) {
            const int m = m0 + wm + mt * 16 + quad * 4;
#pragma unroll
            for (int r = 0; r < 4; r++)
                Cf[(size_t)(m + r) * HID + n] = fmaf(acc[mt][nt][r], gmul[mt][r], bb);
        }
    }
}

// ---------------------------------------------------------------------------
// Pass 1 (MFMA): 128 q-rows/block, 8 thin waves, reg-dbuf K/V staging,
// Qs staging overlays steady region, XCD-swizzled.
// ---------------------------------------------------------------------------
__global__ __launch_bounds__(512) void flash_mfma_kernel(
    const unsigned short* __restrict__ qb, const unsigned short* __restrict__ kb,
    const unsigned short* __restrict__ vt, const unsigned char* __restrict__ mask,
    unsigned short* __restrict__ att, float* __restrict__ zinv_out)
{
    const int n = blockIdx.x;
    const int xcd = n & 7, t = n >> 3;
    const int g = xcd + 8 * (t >> 4);
    const int qblk = t & 15;
    const int h = g & 15, b = g >> 4;
    const int q0 = qblk * 128;

    const int tid = threadIdx.x;
    const int w = tid >> 6, lane = tid & 63;
    const int c = lane & 15, quad = lane >> 4;

    __shared__ unsigned short SM[18048];          // 36096 B
    unsigned short* Ks = SM;                      // [64][72]
    unsigned short* Vs = SM + 4608;               // [64][72]  Vs[d][j]
    unsigned short* Ps = SM + 9216;               // [8][16][68]
    float* mbf = (float*)(SM + 17920);            // [64]
    unsigned short* Qs = SM;                      // staging alias [128][72]

    const size_t hoff = (size_t)h * DHEAD;
#pragma unroll
    for (int it = 0; it < 2; it++) {
        const int gg = it * 512 + tid;
        const int r = gg >> 3, c8 = (gg & 7) << 3;
        *(uint4*)&Qs[r * 72 + c8] =
            *(const uint4*)&qb[(size_t)(b * SEQ + q0 + r) * HID + hoff + c8];
    }
    __syncthreads();
    const short8 aq0 = *(const short8*)&Qs[(w * 16 + c) * 72 + quad * 8];
    const short8 aq1 = *(const short8*)&Qs[(w * 16 + c) * 72 + 32 + quad * 8];

    floatx4 acc_o[4];
#pragma unroll
    for (int dt = 0; dt < 4; dt++) acc_o[dt] = (floatx4){0.f, 0.f, 0.f, 0.f};
    float zp[4] = {0.f, 0.f, 0.f, 0.f};
    const size_t vtbase = (size_t)(b * NHEAD + h) * DHEAD * SEQ;

    const int sr = tid >> 3, sc8 = (tid & 7) << 3;
    uint4 kreg = *(const uint4*)&kb[(size_t)(b * SEQ + sr) * HID + hoff + sc8];
    uint4 vreg = *(const uint4*)&vt[vtbase + (size_t)sr * SEQ + sc8];
    float mreg = 0.f;
    if (tid < 64) mreg = mask[(size_t)b * SEQ + tid] ? -1e9f : 0.f;

    for (int kc = 0; kc < SEQ; kc += 64) {
        __syncthreads();
        *(uint4*)&Ks[sr * 72 + sc8] = kreg;
        *(uint4*)&Vs[sr * 72 + sc8] = vreg;
        if (tid < 64) mbf[tid] = mreg;
        __syncthreads();
        if (kc + 64 < SEQ) {
            kreg = *(const uint4*)&kb[(size_t)(b * SEQ + kc + 64 + sr) * HID + hoff + sc8];
            vreg = *(const uint4*)&vt[vtbase + (size_t)sr * SEQ + kc + 64 + sc8];
            if (tid < 64) mreg = mask[(size_t)b * SEQ + kc + 64 + tid] ? -1e9f : 0.f;
        }

#pragma unroll
        for (int nt = 0; nt < 4; nt++) {
            const short8 bk0 = *(const short8*)&Ks[(nt * 16 + c) * 72 + quad * 8];
            const short8 bk1 = *(const short8*)&Ks[(nt * 16 + c) * 72 + 32 + quad * 8];
            floatx4 s = (floatx4){0.f, 0.f, 0.f, 0.f};
            s = MFMA16(aq0, bk0, s);
            s = MFMA16(aq1, bk1, s);
            const float mb = mbf[nt * 16 + c];
#pragma unroll
            for (int r = 0; r < 4; r++) {
                const float p = EXP2F(fmaf(s[r], SCALE_LOG2E, mb));
                zp[r] += p;
                Ps[(w * 16 + quad * 4 + r) * 68 + nt * 16 + c] = f2bf(p);
            }
        }

        const unsigned short* pr = &Ps[(w * 16 + c) * 68];
        short4v p00 = *(const short4v*)&pr[quad * 8];
        short4v p01 = *(const short4v*)&pr[quad * 8 + 4];
        short4v p10 = *(const short4v*)&pr[32 + quad * 8];
        short4v p11 = *(const short4v*)&pr[32 + quad * 8 + 4];
        const short8 ap0 = __builtin_shufflevector(p00, p01, 0, 1, 2, 3, 4, 5, 6, 7);
        const short8 ap1 = __builtin_shufflevector(p10, p11, 0, 1, 2, 3, 4, 5, 6, 7);
#pragma unroll
        for (int dt = 0; dt < 4; dt++) {
            const short8 bv0 = *(const short8*)&Vs[(dt * 16 + c) * 72 + quad * 8];
            const short8 bv1 = *(const short8*)&Vs[(dt * 16 + c) * 72 + 32 + quad * 8];
            acc_o[dt] = MFMA16(ap0, bv0, acc_o[dt]);
            acc_o[dt] = MFMA16(ap1, bv1, acc_o[dt]);
        }
    }

#pragma unroll
    for (int r = 0; r < 4; r++) {
        float z = zp[r];
        z += __shfl_xor(z, 1, 64); z += __shfl_xor(z, 2, 64);
        z += __shfl_xor(z, 4, 64); z += __shfl_xor(z, 8, 64);
        zp[r] = 1.0f / (z + 1e-30f);
    }

#pragma unroll
    for (int dt = 0; dt < 4; dt++)
#pragma unroll
        for (int r = 0; r < 4; r++)
            att[(size_t)(b * SEQ + q0 + w * 16 + quad * 4 + r) * HID + hoff +
                dt * 16 + c] = f2bf(acc_o[dt][r] * zp[r]);

    if (c == 0) {
        const size_t zb = (size_t)(b * NHEAD + h) * SEQ + q0 + w * 16 + quad * 4;
#pragma unroll
        for (int r = 0; r < 4; r++) zinv_out[zb + r] = zp[r];
    }
}

// ---------------------------------------------------------------------------
// Fused pass 2: blocks [0,512) colsum (MFMA recompute, atomicAdd over heads);
// blocks [512,1024) threshold rows (8 rows/block, one wave each).
// ---------------------------------------------------------------------------
__global__ __launch_bounds__(512) void colsum_thr_kernel(
    const unsigned short* __restrict__ qb, const unsigned short* __restrict__ kb,
    const unsigned char* __restrict__ mask, const float* __restrict__ zinv,
    float* __restrict__ colsum,
    const float* __restrict__ Wt, const float* __restrict__ bt,
    float* __restrict__ thr)
{
    __shared__ unsigned short SM[9216];           // 18432 B
    const int tid = threadIdx.x;
    const int w = tid >> 6, lane = tid & 63;

    if (blockIdx.x >= 512) {                      // ---- threshold branch
        const int row = (blockIdx.x - 512) * 8 + w;
        const unsigned short* qr = qb + (size_t)row * HID;
        const unsigned short* kr = kb + (size_t)row * HID;
        float s = 0.f;
#pragma unroll
        for (int ii = 0; ii < 2; ii++) {
            const int base = ii * 512 + lane * 8;
            const ushort4 q0 = *(const ushort4*)&qr[base];
            const ushort4 q1 = *(const ushort4*)&qr[base + 4];
            const ushort4 k0 = *(const ushort4*)&kr[base];
            const ushort4 k1 = *(const ushort4*)&kr[base + 4];
            const float4 w0 = *(const float4*)&Wt[base];
            const float4 w1 = *(const float4*)&Wt[base + 4];
            s += bf2f(q0.x) * bf2f(k0.x) * w0.x + bf2f(q0.y) * bf2f(k0.y) * w0.y +
                 bf2f(q0.z) * bf2f(k0.z) * w0.z + bf2f(q0.w) * bf2f(k0.w) * w0.w +
                 bf2f(q1.x) * bf2f(k1.x) * w1.x + bf2f(q1.y) * bf2f(k1.y) * w1.y +
                 bf2f(q1.z) * bf2f(k1.z) * w1.z + bf2f(q1.w) * bf2f(k1.w) * w1.w;
        }
#pragma unroll
        for (int off = 32; off > 0; off >>= 1) s += __shfl_xor(s, off, 64);
        if (lane == 0) thr[row] = s + bt[0];
        return;
    }

    // ---- colsum branch
    const int n = blockIdx.x;
    const int xcd = n & 7, t = n >> 3;
    const int g = xcd + 8 * (t >> 4);
    const int h = g & 15, b = g >> 4;
    const int k0 = (t & 15) * 128;
    const int c = lane & 15, quad = lane >> 4;

    unsigned short* Qs = SM;                      // steady [64][72]
    float* zs = (float*)(SM + 4608);              // [64]
    unsigned short* Kst = SM;                     // staging alias [128][72]

    const size_t hoff = (size_t)h * DHEAD;
#pragma unroll
    for (int it = 0; it < 2; it++) {
        const int gg = it * 512 + tid;
        const int r = gg >> 3, c8 = (gg & 7) << 3;
        *(uint4*)&Kst[r * 72 + c8] =
            *(const uint4*)&kb[(size_t)(b * SEQ + k0 + r) * HID + hoff + c8];
    }
    float mb[4];
#pragma unroll
    for (int r = 0; r < 4; r++)
        mb[r] = mask[(size_t)b * SEQ + k0 + w * 16 + quad * 4 + r] ? -1e9f : 0.f;
    __syncthreads();
    const short8 ak0 = *(const short8*)&Kst[(w * 16 + c) * 72 + quad * 8];
    const short8 ak1 = *(const short8*)&Kst[(w * 16 + c) * 72 + 32 + quad * 8];

    float cs[4] = {0.f, 0.f, 0.f, 0.f};
    const size_t zbase = (size_t)(b * NHEAD + h) * SEQ;

    const int sr = tid >> 3, sc8 = (tid & 7) << 3;
    uint4 qreg = *(const uint4*)&qb[(size_t)(b * SEQ + sr) * HID + hoff + sc8];
    float zreg = 0.f;
    if (tid < 64) zreg = zinv[zbase + tid];

    for (int qc = 0; qc < SEQ; qc += 64) {
        __syncthreads();
        *(uint4*)&Qs[sr * 72 + sc8] = qreg;
        if (tid < 64) zs[tid] = zreg;
        __syncthreads();
        if (qc + 64 < SEQ) {
            qreg = *(const uint4*)&qb[(size_t)(b * SEQ + qc + 64 + sr) * HID + hoff + sc8];
            if (tid < 64) zreg = zinv[zbase + qc + 64 + tid];
        }

#pragma unroll
        for (int qt = 0; qt < 4; qt++) {
            const short8 bq0 = *(const short8*)&Qs[(qt * 16 + c) * 72 + quad * 8];
            const short8 bq1 = *(const short8*)&Qs[(qt * 16 + c) * 72 + 32 + quad * 8];
            floatx4 s = (floatx4){0.f, 0.f, 0.f, 0.f};
            s = MFMA16(ak0, bq0, s);
            s = MFMA16(ak1, bq1, s);
            const float zi = zs[qt * 16 + c];
#pragma unroll
            for (int r = 0; r < 4; r++)
                cs[r] += EXP2F(fmaf(s[r], SCALE_LOG2E, mb[r])) * zi;
        }
    }

#pragma unroll
    for (int r = 0; r < 4; r++) {
        float v = cs[r];
        v += __shfl_xor(v, 1, 64); v += __shfl_xor(v, 2, 64);
        v += __shfl_xor(v, 4, 64); v += __shfl_xor(v, 8, 64);
        if (c == 0)
            atomicAdd(&colsum[(size_t)b * SEQ + k0 + w * 16 + quad * 4 + r], v);
    }
}

// ---------------------------------------------------------------------------
extern "C" void kernel_launch(void* const* d_in, const int* in_sizes, int n_in,
                              void* d_out, int out_size, void* d_ws, size_t ws_size,
                              hipStream_t stream)
{
    const float* v  = (const float*)d_in[0];
    const float* k  = (const float*)d_in[1];
    const float* q  = (const float*)d_in[2];
    const unsigned char* mask = (const unsigned char*)d_in[3];
    const float* Wv = (const float*)d_in[4];
    const float* bv = (const float*)d_in[5];
    const float* Wk = (const float*)d_in[6];
    const float* bk = (const float*)d_in[7];
    const float* Wq = (const float*)d_in[8];
    const float* bq = (const float*)d_in[9];
    const float* Wt = (const float*)d_in[10];
    const float* bt = (const float*)d_in[11];
    const float* Wm = (const float*)d_in[12];
    const float* bm = (const float*)d_in[13];
    float* out = (float*)d_out;

    const size_t NE = (size_t)MROWS * HID;
    const size_t WE = (size_t)HID * HID;
    unsigned short* qa   = (unsigned short*)d_ws;
    unsigned short* ka   = qa  + NE;
    unsigned short* va   = ka  + NE;
    unsigned short* qp   = va  + NE;
    unsigned short* kp   = qp  + NE;
    unsigned short* vtb  = kp  + NE;
    unsigned short* WqT  = vtb + NE;
    unsigned short* WkT  = WqT + WE;
    unsigned short* WvT  = WkT + WE;
    unsigned short* WmT  = WvT + WE;
    float* thr    = (float*)(WmT + WE);
    float* zinv   = thr  + MROWS;
    float* colsum = zinv + (size_t)BATCH * NHEAD * SEQ;
    // attb aliases qa: qa is only read by proj3 (z=0), dead before flash runs
    unsigned short* attb = qa;

    prep_kernel<<<7170, 256, 0, stream>>>(q, k, v, qa, ka, va,
                                          Wq, Wk, Wv, Wm, WqT, WkT, WvT, WmT,
                                          colsum);

    proj3_mfma_kernel<<<dim3(MROWS / 128, HID / 128, 3), 256, 0, stream>>>(
        qa, ka, va, WqT, WkT, WvT, bq, bk, bv, qp, kp, vtb);

    flash_mfma_kernel<<<BATCH * NHEAD * (SEQ / 128), 512, 0, stream>>>(
        qp, kp, vtb, mask, attb, zinv);

    colsum_thr_kernel<<<1024, 512, 0, stream>>>(
        qp, kp, mask, zinv, colsum, Wt, bt, thr);

    gemm_gate_kernel<<<dim3(MROWS / 128, HID / 128), 256, 0, stream>>>(
        attb, WmT, bm, colsum, thr, out);
}